// Round 9
// baseline (173.312 us; speedup 1.0000x reference)
//
#include <hip/hip_runtime.h>
#include <hip/hip_bf16.h>
#include <math.h>

#define H_DIM 128
#define W_DIM 128
#define BATCH 4
#define HW (H_DIM * W_DIM)

typedef __attribute__((ext_vector_type(8))) short bf16x8;
typedef __attribute__((ext_vector_type(4))) float f32x4;
typedef __attribute__((ext_vector_type(4))) unsigned int u32x4;

static __device__ __forceinline__ unsigned short f2bf(float f) {
    __hip_bfloat16 h = __float2bfloat16(f);   // RNE
    return *reinterpret_cast<unsigned short*>(&h);
}
static __device__ __forceinline__ float bf2f(unsigned short u) {
    return __uint_as_float(((unsigned int)u) << 16);
}

// ---------------------------------------------------------------------------
// Build swizzled-NHWC bf16 concat input [B][H][W][128] via LDS transpose.
// Swizzle: true channel-unit ut (8 bf16 = 16B) of column x stored at unit
// position (ut&8) | ((ut&7) ^ ((x+1)&7)).
// ---------------------------------------------------------------------------
__global__ __launch_bounds__(256)
void prep_nhwc_kernel(const float* __restrict__ nbr, const float* __restrict__ ref,
                      unsigned short* __restrict__ dst) {
    __shared__ float s[128][65];   // 33.3 KB
    const int b  = blockIdx.y;
    const int p0 = blockIdx.x * 64;          // aligned 64 px, same row y
    const int t  = threadIdx.x;
    const int px = t & 63;
#pragma unroll
    for (int it = 0; it < 32; ++it) {
        int c = it * 4 + (t >> 6);           // 0..127
        const float* src = (c < 64) ? nbr : ref;
        int cs = c & 63;
        s[c][px] = src[(size_t)(b * 64 + cs) * HW + p0 + px];
    }
    __syncthreads();
#pragma unroll
    for (int it = 0; it < 4; ++it) {
        int idx = it * 256 + t;              // p*16 + ut
        int p  = idx >> 4;
        int ut = idx & 15;
        int x  = (p0 + p) & 127;
        int key = (x + 1) & 7;
        int cpos = (ut & 8) | ((ut & 7) ^ key);
        bf16x8 v;
#pragma unroll
        for (int j = 0; j < 8; ++j)
            v[j] = (short)f2bf(s[ut * 8 + j][p]);
        *(bf16x8*)(dst + ((size_t)(b * HW + p0 + p) * 128 + cpos * 8)) = v;
    }
}

// ---------------------------------------------------------------------------
// Plain NHWC bf16 copy of nbr: [B][HW][64]. LDS-transposed for coalescing.
// ---------------------------------------------------------------------------
__global__ __launch_bounds__(256)
void prep_nbr_nhwc_kernel(const float* __restrict__ nbr,
                          unsigned short* __restrict__ dst) {
    __shared__ float s[64][65];
    const int b  = blockIdx.y;
    const int p0 = blockIdx.x * 64;
    const int t  = threadIdx.x;
#pragma unroll
    for (int it = 0; it < 16; ++it) {
        int c = it * 4 + (t >> 6);
        s[c][t & 63] = nbr[(size_t)(b * 64 + c) * HW + p0 + (t & 63)];
    }
    __syncthreads();
#pragma unroll
    for (int it = 0; it < 2; ++it) {
        int idx = it * 256 + t;       // px*8 + unit
        int px = idx >> 3;
        int u  = idx & 7;
        bf16x8 v;
#pragma unroll
        for (int j = 0; j < 8; ++j)
            v[j] = (short)f2bf(s[u * 8 + j][px]);
        *(bf16x8*)(dst + ((size_t)(b * HW + p0 + px) * 64 + u * 8)) = v;
    }
}

// ---------------------------------------------------------------------------
// Pack conv weights [COUT][CIN][3][3] fp32 -> MFMA B-fragment order bf16.
// ---------------------------------------------------------------------------
__global__ void pack_w_kernel(const float* __restrict__ w, unsigned short* __restrict__ dst,
                              int COUT_real, int CIN, int NCF, int NKS) {
    int idx = blockIdx.x * 256 + threadIdx.x;
    int total = NKS * NCF * 64 * 8;
    if (idx >= total) return;
    int j    = idx & 7;
    int lane = (idx >> 3) & 63;
    int frag = idx >> 9;
    int cf   = frag % NCF;
    int ks   = frag / NCF;
    int co = cf * 16 + (lane & 15);
    int k  = ks * 32 + (lane >> 4) * 8 + j;
    int t  = k / CIN;
    int ci = k % CIN;
    float v = (co < COUT_real) ? w[((size_t)co * CIN + ci) * 9 + t] : 0.f;
    dst[idx] = f2bf(v);
}

// ---------------------------------------------------------------------------
// Implicit-GEMM 3x3 SAME conv via bf16 MFMA (conv1 / conv2).
// ---------------------------------------------------------------------------
template<int CIN, int NKS, bool RELU>
__global__ __launch_bounds__(256)
void conv_mfma_kernel(const unsigned short* __restrict__ in,   // swizzled NHWC bf16
                      const unsigned short* __restrict__ wpk,  // packed weight frags
                      const float* __restrict__ bias,
                      unsigned short* __restrict__ out)
{
    static_assert(CIN % 32 == 0, "CIN must be multiple of 32");
    constexpr int ROWB = 132 * CIN * 2;      // bytes per dy row in LDS
    __shared__ __align__(16) char smem[3 * ROWB];

    const int rb  = blockIdx.x;        // b*H + y
    const int b   = rb >> 7;
    const int y   = rb & 127;
    const int tid  = threadIdx.x;
    const int lane = tid & 63;
    const int wave = tid >> 6;
    const int l15  = lane & 15;
    const int q    = lane >> 4;
    const u32x4 zv = {0u, 0u, 0u, 0u};

    for (int dy = 0; dy < 3; ++dy) {
        int yy = y + dy - 1;
        char* dstrow = smem + dy * ROWB;
        if (yy >= 0 && yy < H_DIM) {
            const char* src = (const char*)(in + ((size_t)(b * H_DIM + yy) * W_DIM) * CIN);
            for (int i = tid * 16; i < 128 * CIN * 2; i += 256 * 16)
                *(u32x4*)(dstrow + CIN * 2 + i) = *(const u32x4*)(src + i);
            for (int i = tid; i < 2 * (CIN / 8); i += 256) {
                int col = (i < CIN / 8) ? 0 : 129;
                int u   = i % (CIN / 8);
                *(u32x4*)(dstrow + (col * CIN + u * 8) * 2) = zv;
            }
        } else {
            for (int i = tid * 16; i < 130 * CIN * 2; i += 256 * 16)
                *(u32x4*)(dstrow + i) = zv;
        }
    }
    __syncthreads();

    f32x4 acc[2][4];
#pragma unroll
    for (int pf = 0; pf < 2; ++pf)
#pragma unroll
        for (int cf = 0; cf < 4; ++cf)
            acc[pf][cf] = (f32x4){0.f, 0.f, 0.f, 0.f};

    const int px0 = wave * 32;
#pragma unroll
    for (int ks = 0; ks < NKS; ++ks) {
        const int t   = ks / (CIN / 32);
        const int ci0 = (ks % (CIN / 32)) * 32;
        const int dy = t / 3, dx = t % 3;
        bf16x8 a[2];
#pragma unroll
        for (int pf = 0; pf < 2; ++pf) {
            int gx = px0 + pf * 16 + l15 + dx;
            int upos = ((ci0 >> 3) + q) ^ (gx & 7);
            a[pf] = *(const bf16x8*)(smem + dy * ROWB + (gx * CIN + upos * 8) * 2);
        }
        bf16x8 wfr[4];
#pragma unroll
        for (int cf = 0; cf < 4; ++cf)
            wfr[cf] = *(const bf16x8*)(wpk + ((size_t)(ks * 4 + cf) * 64 + lane) * 8);
#pragma unroll
        for (int pf = 0; pf < 2; ++pf)
#pragma unroll
            for (int cf = 0; cf < 4; ++cf)
                acc[pf][cf] = __builtin_amdgcn_mfma_f32_16x16x32_bf16(
                    a[pf], wfr[cf], acc[pf][cf], 0, 0, 0);
    }

#pragma unroll
    for (int pf = 0; pf < 2; ++pf)
#pragma unroll
        for (int cf = 0; cf < 4; ++cf) {
            const int co = cf * 16 + l15;
            const float bv = bias[co];
#pragma unroll
            for (int r = 0; r < 4; ++r) {
                int x = px0 + pf * 16 + q * 4 + r;
                float v = acc[pf][cf][r] + bv;
                if (RELU) v = (v >= 0.f) ? v : 0.1f * v;
                int cpos = (((co >> 3) ^ ((x + 1) & 7)) << 3) | (co & 7);
                out[((size_t)(b * H_DIM + y) * W_DIM + x) * 64 + cpos] = f2bf(v);
            }
        }
}

// ---------------------------------------------------------------------------
// conv3 (216 couts) -> om bf16 [B][216][HW] global, coalesced via LDS.
// Block = (b, y, half): 64 pixels, 4 waves; waves split couts (R7).
// ---------------------------------------------------------------------------
__global__ __launch_bounds__(256, 4)
void conv3om_kernel(const unsigned short* __restrict__ in,   // c2o swizzled NHWC
                    const unsigned short* __restrict__ wpk3, // [18][14][64][8]
                    const float* __restrict__ bom,
                    unsigned short* __restrict__ omg)        // bf16 [B][216][HW]
{
    constexpr int ROWB = 66 * 128;                 // staging bytes per dy row
    __shared__ __align__(16) char smem[216 * 72 * 2];   // 31104 B union
    unsigned short* om_lds = (unsigned short*)smem;

    const int rb   = blockIdx.x;        // ((b*H + y)<<1) | half
    const int x0   = (rb & 1) * 64;
    const int y    = (rb >> 1) & 127;
    const int b    = rb >> 8;
    const int tid  = threadIdx.x;
    const int lane = tid & 63;
    const int wave = tid >> 6;          // cout-frag base
    const int l15  = lane & 15;
    const int q    = lane >> 4;
    const u32x4 zv = {0u, 0u, 0u, 0u};

    // ---- stage 3 rows x 66 cols (LDS col l <-> global x0-1+l) ----
    const int lstart = (x0 == 0) ? 1 : 0;
    const int lzero  = (x0 == 0) ? 0 : 65;
    for (int dy = 0; dy < 3; ++dy) {
        int yy = y + dy - 1;
        char* dstrow = smem + dy * ROWB;
        if (yy >= 0 && yy < H_DIM) {
            const char* src = (const char*)(in +
                ((size_t)(b * H_DIM + yy) * W_DIM + (x0 - 1 + lstart)) * 64);
            for (int i = tid * 16; i < 65 * 128; i += 256 * 16)
                *(u32x4*)(dstrow + lstart * 128 + i) = *(const u32x4*)(src + i);
            if (tid < 8)
                *(u32x4*)(dstrow + lzero * 128 + tid * 16) = zv;
        } else {
            for (int i = tid * 16; i < 66 * 128; i += 256 * 16)
                *(u32x4*)(dstrow + i) = zv;
        }
    }
    __syncthreads();

    // ---- conv3: wave w -> cf {w, w+4, w+8, w+12} (cf<14), all 64 px ----
    f32x4 acc[4][4];   // [pf][cfi]
#pragma unroll
    for (int pf = 0; pf < 4; ++pf)
#pragma unroll
        for (int cfi = 0; cfi < 4; ++cfi)
            acc[pf][cfi] = (f32x4){0.f, 0.f, 0.f, 0.f};

#pragma unroll
    for (int ks = 0; ks < 18; ++ks) {
        const int t   = ks >> 1;
        const int ci0 = (ks & 1) * 32;
        const int dy = t / 3, dx = t % 3;
        bf16x8 a[4];
#pragma unroll
        for (int pf = 0; pf < 4; ++pf) {
            const int l = pf * 16 + l15 + dx;
            const int upos = ((ci0 >> 3) + q) ^ (l & 7);
            a[pf] = *(const bf16x8*)(smem + dy * ROWB + (l * 64 + upos * 8) * 2);
        }
#pragma unroll
        for (int cfi = 0; cfi < 4; ++cfi) {
            const int cf = wave + cfi * 4;
            if (cfi < 3 || wave < 2) {            // cf < 14 (wave-uniform)
                bf16x8 wfr = *(const bf16x8*)(wpk3 + ((size_t)(ks * 14 + cf) * 64 + lane) * 8);
#pragma unroll
                for (int pf = 0; pf < 4; ++pf)
                    acc[pf][cfi] = __builtin_amdgcn_mfma_f32_16x16x32_bf16(
                        a[pf], wfr, acc[pf][cfi], 0, 0, 0);
            }
        }
    }
    __syncthreads();   // staging dead; om region aliases it

    // ---- om slices -> LDS bf16 [216][72] (wave w writes its cf rows) ----
#pragma unroll
    for (int cfi = 0; cfi < 4; ++cfi) {
        const int cf = wave + cfi * 4;
        if (cfi < 3 || wave < 2) {
            const int co = cf * 16 + l15;
            const float bv = (co < 216) ? bom[co] : 0.f;
            if (co < 216) {
#pragma unroll
                for (int pf = 0; pf < 4; ++pf)
#pragma unroll
                    for (int r = 0; r < 4; ++r) {
                        int xl = pf * 16 + q * 4 + r;
                        om_lds[co * 72 + xl] = f2bf(acc[pf][cfi][r] + bv);
                    }
            }
        }
    }
    __syncthreads();

    // ---- dump LDS -> global, 16B coalesced ----
    unsigned short* dst = omg + (size_t)b * 216 * HW + y * W_DIM + x0;
    for (int i = tid; i < 216 * 8; i += 256) {
        int row = i >> 3;
        int seg = i & 7;
        u32x4 v = *(const u32x4*)(om_lds + row * 72 + seg * 8);
        *(u32x4*)(dst + (size_t)row * HW + seg * 8) = v;
    }
}

// ---------------------------------------------------------------------------
// Modulated deformable conv, implicit GEMM, K-SPLIT across waves.
// Block = (b, y, quarter): 32 px, 256 threads = 4 waves =
//   {pxgrp 0/1 (16 px each)} x {khalf 0/1 (9 of 18 k-steps each)}.
// 2048 blocks -> 8192 waves -> 8 waves/SIMD (2x R7) and each wave's serial
// om->gather->interp chain halves (9 iters). Partial sums exchanged via LDS
// (padded stride, conflict-free); khalf=0 adds + stores.
// ---------------------------------------------------------------------------
__global__ __launch_bounds__(256, 8)
void deform_mfma_kernel(const unsigned short* __restrict__ xh,  // nbr [B][HW][64] bf16
                        const unsigned short* __restrict__ omg, // bf16 [B][216][HW]
                        const unsigned short* __restrict__ wpkD,// [18][4][64][8]
                        const float* __restrict__ bdcn,
                        float* __restrict__ out)
{
    __shared__ __align__(16) float red[2][64][5][4];   // 10240 B (pad 5: no bank conflict)

    const int rb    = blockIdx.x;       // ((b*H + y)<<2) | quarter
    const int x0    = (rb & 3) * 32;
    const int y     = (rb >> 2) & 127;
    const int b     = rb >> 9;
    const int tid   = threadIdx.x;
    const int lane  = tid & 63;
    const int wave  = tid >> 6;
    const int pxgrp = wave & 1;
    const int khalf = wave >> 1;
    const int l15   = lane & 15;
    const int q     = lane >> 4;
    const int px0w  = pxgrp * 16;

    const unsigned short* xb  = xh + (size_t)b * HW * 64;
    const unsigned short* omb = omg + (size_t)b * 216 * HW;
    const int x   = x0 + px0w + l15;
    const int pix = y * W_DIM + x;

    f32x4 acc2[4];
#pragma unroll
    for (int cf = 0; cf < 4; ++cf)
        acc2[cf] = (f32x4){0.f, 0.f, 0.f, 0.f};

    auto body = [&](int ks) {
        const int tap = ks >> 1;
        const int g   = (ks & 1) * 4 + q;
        const int och = g * 9 + tap;
        const int dy  = tap / 3 - 1;
        const int dx  = tap % 3 - 1;

        const float offy = bf2f(omb[(size_t)och * HW + pix]);
        const float offx = bf2f(omb[(size_t)(72 + och) * HW + pix]);
        const float mraw = bf2f(omb[(size_t)(144 + och) * HW + pix]);
        const float mask = 1.f / (1.f + __expf(-mraw));

        const float sy = offy + (float)(dy + y);
        const float sx = offx + (float)(dx + x);
        const float fy = floorf(sy);
        const float fx = floorf(sx);
        const int y0 = (int)fy;
        const int xq0 = (int)fx;
        const float ay = sy - fy;
        const float ax = sx - fx;

        const bool vy0 = (y0 >= 0) && (y0 < H_DIM);
        const bool vy1 = (y0 >= -1) && (y0 < H_DIM - 1);
        const bool vx0 = (xq0 >= 0) && (xq0 < W_DIM);
        const bool vx1 = (xq0 >= -1) && (xq0 < W_DIM - 1);

        float w00 = (1.f - ay) * (1.f - ax); if (!(vy0 && vx0)) w00 = 0.f;
        float w01 = (1.f - ay) * ax;         if (!(vy0 && vx1)) w01 = 0.f;
        float w10 = ay * (1.f - ax);         if (!(vy1 && vx0)) w10 = 0.f;
        float w11 = ay * ax;                 if (!(vy1 && vx1)) w11 = 0.f;
        w00 *= mask; w01 *= mask; w10 *= mask; w11 *= mask;

        const int iy0 = min(max(y0, 0), H_DIM - 1);
        const int iy1 = min(max(y0 + 1, 0), H_DIM - 1);
        const int ix0 = min(max(xq0, 0), W_DIM - 1);
        const int ix1 = min(max(xq0 + 1, 0), W_DIM - 1);

        const unsigned short* gb = xb + g * 8;
        const bf16x8 c00 = *(const bf16x8*)(gb + (size_t)(iy0 * W_DIM + ix0) * 64);
        const bf16x8 c01 = *(const bf16x8*)(gb + (size_t)(iy0 * W_DIM + ix1) * 64);
        const bf16x8 c10 = *(const bf16x8*)(gb + (size_t)(iy1 * W_DIM + ix0) * 64);
        const bf16x8 c11 = *(const bf16x8*)(gb + (size_t)(iy1 * W_DIM + ix1) * 64);

        bf16x8 av;
#pragma unroll
        for (int j = 0; j < 8; ++j) {
            float v = w00 * bf2f((unsigned short)c00[j])
                    + w01 * bf2f((unsigned short)c01[j])
                    + w10 * bf2f((unsigned short)c10[j])
                    + w11 * bf2f((unsigned short)c11[j]);
            av[j] = (short)f2bf(v);
        }

#pragma unroll
        for (int cf = 0; cf < 4; ++cf) {
            bf16x8 wfr = *(const bf16x8*)(wpkD + ((size_t)(ks * 4 + cf) * 64 + lane) * 8);
            acc2[cf] = __builtin_amdgcn_mfma_f32_16x16x32_bf16(av, wfr, acc2[cf], 0, 0, 0);
        }
    };

    if (khalf == 0) {
#pragma unroll
        for (int ks = 0; ks < 9; ++ks) body(ks);
    } else {
#pragma unroll
        for (int ks = 9; ks < 18; ++ks) body(ks);
    }

    // ---- K-split reduction: khalf1 -> LDS, khalf0 adds + stores ----
    if (khalf == 1) {
#pragma unroll
        for (int cf = 0; cf < 4; ++cf)
            *(f32x4*)&red[pxgrp][lane][cf][0] = acc2[cf];
    }
    __syncthreads();
    if (khalf == 0) {
#pragma unroll
        for (int cf = 0; cf < 4; ++cf) {
            const f32x4 other = *(const f32x4*)&red[pxgrp][lane][cf][0];
            const int co = cf * 16 + l15;
            const float bv = bdcn[co];
#pragma unroll
            for (int r = 0; r < 4; ++r) {
                int xs = x0 + px0w + q * 4 + r;
                out[(size_t)(b * 64 + co) * HW + y * W_DIM + xs] =
                    acc2[cf][r] + other[r] + bv;
            }
        }
    }
}

// ---------------------------------------------------------------------------
// Launcher. Workspace (bytes):
//   [0, 16.8M)        in1 swizzled-NHWC bf16
//   [16.8M, 25.2M)    c1o
//   [25.2M, 33.6M)    c2o
//   [33.6M, 42.0M)    nbrh bf16-NHWC
//   [42.0M, 70.3M)    omg bf16 [B][216][HW] (28.3M)
//   [70.3M, ...)      wpk1, wpk2, wpk3, wpkD
// ---------------------------------------------------------------------------
extern "C" void kernel_launch(void* const* d_in, const int* in_sizes, int n_in,
                              void* d_out, int out_size, void* d_ws, size_t ws_size,
                              hipStream_t stream) {
    const float* nbr  = (const float*)d_in[0];
    const float* ref  = (const float*)d_in[1];
    const float* w1   = (const float*)d_in[2];
    const float* b1   = (const float*)d_in[3];
    const float* w2   = (const float*)d_in[4];
    const float* b2   = (const float*)d_in[5];
    const float* wom  = (const float*)d_in[6];
    const float* bom  = (const float*)d_in[7];
    const float* wdcn = (const float*)d_in[8];
    const float* bdcn = (const float*)d_in[9];
    float* out = (float*)d_out;
    char* W = (char*)d_ws;

    unsigned short* in1  = (unsigned short*)(W + 0);
    unsigned short* c1o  = (unsigned short*)(W + 16777216);
    unsigned short* c2o  = (unsigned short*)(W + 25165824);
    unsigned short* nbrh = (unsigned short*)(W + 33554432);
    unsigned short* omg  = (unsigned short*)(W + 41943040);
    unsigned short* wpk1 = (unsigned short*)(W + 70254592);
    unsigned short* wpk2 = (unsigned short*)(W + 70402048);
    unsigned short* wpk3 = (unsigned short*)(W + 70475776);
    unsigned short* wpkD = (unsigned short*)(W + 70733824);

    prep_nhwc_kernel<<<dim3(HW / 64, BATCH), 256, 0, stream>>>(nbr, ref, in1);
    pack_w_kernel<<<288, 256, 0, stream>>>(w1, wpk1, 64, 128, 4, 36);
    pack_w_kernel<<<144, 256, 0, stream>>>(w2, wpk2, 64, 64, 4, 18);
    pack_w_kernel<<<504, 256, 0, stream>>>(wom, wpk3, 216, 64, 14, 18);
    pack_w_kernel<<<144, 256, 0, stream>>>(wdcn, wpkD, 64, 64, 4, 18);
    prep_nbr_nhwc_kernel<<<dim3(HW / 64, BATCH), 256, 0, stream>>>(nbr, nbrh);

    // conv1: concat(nbr,ref) 128ch -> 64, lrelu
    conv_mfma_kernel<128, 36, true>
        <<<dim3(BATCH * H_DIM), 256, 0, stream>>>(in1, wpk1, b1, c1o);
    // conv2: 64 -> 64, lrelu
    conv_mfma_kernel<64, 18, true>
        <<<dim3(BATCH * H_DIM), 256, 0, stream>>>(c1o, wpk2, b2, c2o);

    // conv3 -> om bf16 global (coalesced, cout-split waves)
    conv3om_kernel<<<dim3(BATCH * H_DIM * 2), 256, 0, stream>>>(
        c2o, wpk3, bom, omg);
    // deformable conv (K-split waves, 8 waves/SIMD)
    deform_mfma_kernel<<<dim3(BATCH * H_DIM * 4), 256, 0, stream>>>(
        nbrh, omg, wpkD, bdcn, out);
}

// Round 10
// 149.558 us; speedup vs baseline: 1.1588x; 1.1588x over previous
//
#include <hip/hip_runtime.h>
#include <hip/hip_bf16.h>
#include <math.h>

#define H_DIM 128
#define W_DIM 128
#define BATCH 4
#define HW (H_DIM * W_DIM)

typedef __attribute__((ext_vector_type(8))) short bf16x8;
typedef __attribute__((ext_vector_type(4))) float f32x4;
typedef __attribute__((ext_vector_type(4))) unsigned int u32x4;

static __device__ __forceinline__ unsigned short f2bf(float f) {
    __hip_bfloat16 h = __float2bfloat16(f);   // RNE
    return *reinterpret_cast<unsigned short*>(&h);
}
static __device__ __forceinline__ float bf2f(unsigned short u) {
    return __uint_as_float(((unsigned int)u) << 16);
}

// ---------------------------------------------------------------------------
// Build swizzled-NHWC bf16 concat input [B][H][W][128] via LDS transpose.
// Swizzle: true channel-unit ut (8 bf16 = 16B) of column x stored at unit
// position (ut&8) | ((ut&7) ^ ((x+1)&7)).
// ---------------------------------------------------------------------------
__global__ __launch_bounds__(256)
void prep_nhwc_kernel(const float* __restrict__ nbr, const float* __restrict__ ref,
                      unsigned short* __restrict__ dst) {
    __shared__ float s[128][65];   // 33.3 KB
    const int b  = blockIdx.y;
    const int p0 = blockIdx.x * 64;          // aligned 64 px, same row y
    const int t  = threadIdx.x;
    const int px = t & 63;
#pragma unroll
    for (int it = 0; it < 32; ++it) {
        int c = it * 4 + (t >> 6);           // 0..127
        const float* src = (c < 64) ? nbr : ref;
        int cs = c & 63;
        s[c][px] = src[(size_t)(b * 64 + cs) * HW + p0 + px];
    }
    __syncthreads();
#pragma unroll
    for (int it = 0; it < 4; ++it) {
        int idx = it * 256 + t;              // p*16 + ut
        int p  = idx >> 4;
        int ut = idx & 15;
        int x  = (p0 + p) & 127;
        int key = (x + 1) & 7;
        int cpos = (ut & 8) | ((ut & 7) ^ key);
        bf16x8 v;
#pragma unroll
        for (int j = 0; j < 8; ++j)
            v[j] = (short)f2bf(s[ut * 8 + j][p]);
        *(bf16x8*)(dst + ((size_t)(b * HW + p0 + p) * 128 + cpos * 8)) = v;
    }
}

// ---------------------------------------------------------------------------
// Plain NHWC bf16 copy of nbr: [B][HW][64]. LDS-transposed for coalescing.
// ---------------------------------------------------------------------------
__global__ __launch_bounds__(256)
void prep_nbr_nhwc_kernel(const float* __restrict__ nbr,
                          unsigned short* __restrict__ dst) {
    __shared__ float s[64][65];
    const int b  = blockIdx.y;
    const int p0 = blockIdx.x * 64;
    const int t  = threadIdx.x;
#pragma unroll
    for (int it = 0; it < 16; ++it) {
        int c = it * 4 + (t >> 6);
        s[c][t & 63] = nbr[(size_t)(b * 64 + c) * HW + p0 + (t & 63)];
    }
    __syncthreads();
#pragma unroll
    for (int it = 0; it < 2; ++it) {
        int idx = it * 256 + t;       // px*8 + unit
        int px = idx >> 3;
        int u  = idx & 7;
        bf16x8 v;
#pragma unroll
        for (int j = 0; j < 8; ++j)
            v[j] = (short)f2bf(s[u * 8 + j][px]);
        *(bf16x8*)(dst + ((size_t)(b * HW + p0 + px) * 64 + u * 8)) = v;
    }
}

// ---------------------------------------------------------------------------
// Pack conv weights [COUT][CIN][3][3] fp32 -> MFMA B-fragment order bf16.
// ---------------------------------------------------------------------------
__global__ void pack_w_kernel(const float* __restrict__ w, unsigned short* __restrict__ dst,
                              int COUT_real, int CIN, int NCF, int NKS) {
    int idx = blockIdx.x * 256 + threadIdx.x;
    int total = NKS * NCF * 64 * 8;
    if (idx >= total) return;
    int j    = idx & 7;
    int lane = (idx >> 3) & 63;
    int frag = idx >> 9;
    int cf   = frag % NCF;
    int ks   = frag / NCF;
    int co = cf * 16 + (lane & 15);
    int k  = ks * 32 + (lane >> 4) * 8 + j;
    int t  = k / CIN;
    int ci = k % CIN;
    float v = (co < COUT_real) ? w[((size_t)co * CIN + ci) * 9 + t] : 0.f;
    dst[idx] = f2bf(v);
}

// ---------------------------------------------------------------------------
// Implicit-GEMM 3x3 SAME conv via bf16 MFMA (conv1 / conv2).
// ---------------------------------------------------------------------------
template<int CIN, int NKS, bool RELU>
__global__ __launch_bounds__(256)
void conv_mfma_kernel(const unsigned short* __restrict__ in,   // swizzled NHWC bf16
                      const unsigned short* __restrict__ wpk,  // packed weight frags
                      const float* __restrict__ bias,
                      unsigned short* __restrict__ out)
{
    static_assert(CIN % 32 == 0, "CIN must be multiple of 32");
    constexpr int ROWB = 132 * CIN * 2;      // bytes per dy row in LDS
    __shared__ __align__(16) char smem[3 * ROWB];

    const int rb  = blockIdx.x;        // b*H + y
    const int b   = rb >> 7;
    const int y   = rb & 127;
    const int tid  = threadIdx.x;
    const int lane = tid & 63;
    const int wave = tid >> 6;
    const int l15  = lane & 15;
    const int q    = lane >> 4;
    const u32x4 zv = {0u, 0u, 0u, 0u};

    for (int dy = 0; dy < 3; ++dy) {
        int yy = y + dy - 1;
        char* dstrow = smem + dy * ROWB;
        if (yy >= 0 && yy < H_DIM) {
            const char* src = (const char*)(in + ((size_t)(b * H_DIM + yy) * W_DIM) * CIN);
            for (int i = tid * 16; i < 128 * CIN * 2; i += 256 * 16)
                *(u32x4*)(dstrow + CIN * 2 + i) = *(const u32x4*)(src + i);
            for (int i = tid; i < 2 * (CIN / 8); i += 256) {
                int col = (i < CIN / 8) ? 0 : 129;
                int u   = i % (CIN / 8);
                *(u32x4*)(dstrow + (col * CIN + u * 8) * 2) = zv;
            }
        } else {
            for (int i = tid * 16; i < 130 * CIN * 2; i += 256 * 16)
                *(u32x4*)(dstrow + i) = zv;
        }
    }
    __syncthreads();

    f32x4 acc[2][4];
#pragma unroll
    for (int pf = 0; pf < 2; ++pf)
#pragma unroll
        for (int cf = 0; cf < 4; ++cf)
            acc[pf][cf] = (f32x4){0.f, 0.f, 0.f, 0.f};

    const int px0 = wave * 32;
#pragma unroll
    for (int ks = 0; ks < NKS; ++ks) {
        const int t   = ks / (CIN / 32);
        const int ci0 = (ks % (CIN / 32)) * 32;
        const int dy = t / 3, dx = t % 3;
        bf16x8 a[2];
#pragma unroll
        for (int pf = 0; pf < 2; ++pf) {
            int gx = px0 + pf * 16 + l15 + dx;
            int upos = ((ci0 >> 3) + q) ^ (gx & 7);
            a[pf] = *(const bf16x8*)(smem + dy * ROWB + (gx * CIN + upos * 8) * 2);
        }
        bf16x8 wfr[4];
#pragma unroll
        for (int cf = 0; cf < 4; ++cf)
            wfr[cf] = *(const bf16x8*)(wpk + ((size_t)(ks * 4 + cf) * 64 + lane) * 8);
#pragma unroll
        for (int pf = 0; pf < 2; ++pf)
#pragma unroll
            for (int cf = 0; cf < 4; ++cf)
                acc[pf][cf] = __builtin_amdgcn_mfma_f32_16x16x32_bf16(
                    a[pf], wfr[cf], acc[pf][cf], 0, 0, 0);
    }

#pragma unroll
    for (int pf = 0; pf < 2; ++pf)
#pragma unroll
        for (int cf = 0; cf < 4; ++cf) {
            const int co = cf * 16 + l15;
            const float bv = bias[co];
#pragma unroll
            for (int r = 0; r < 4; ++r) {
                int x = px0 + pf * 16 + q * 4 + r;
                float v = acc[pf][cf][r] + bv;
                if (RELU) v = (v >= 0.f) ? v : 0.1f * v;
                int cpos = (((co >> 3) ^ ((x + 1) & 7)) << 3) | (co & 7);
                out[((size_t)(b * H_DIM + y) * W_DIM + x) * 64 + cpos] = f2bf(v);
            }
        }
}

// ---------------------------------------------------------------------------
// conv3 (216 couts) -> om bf16 [B][216][HW] global, coalesced via LDS.
// Block = (b, y, half): 64 pixels, 4 waves; waves split couts (R7).
// ---------------------------------------------------------------------------
__global__ __launch_bounds__(256, 4)
void conv3om_kernel(const unsigned short* __restrict__ in,   // c2o swizzled NHWC
                    const unsigned short* __restrict__ wpk3, // [18][14][64][8]
                    const float* __restrict__ bom,
                    unsigned short* __restrict__ omg)        // bf16 [B][216][HW]
{
    constexpr int ROWB = 66 * 128;                 // staging bytes per dy row
    __shared__ __align__(16) char smem[216 * 72 * 2];   // 31104 B union
    unsigned short* om_lds = (unsigned short*)smem;

    const int rb   = blockIdx.x;        // ((b*H + y)<<1) | half
    const int x0   = (rb & 1) * 64;
    const int y    = (rb >> 1) & 127;
    const int b    = rb >> 8;
    const int tid  = threadIdx.x;
    const int lane = tid & 63;
    const int wave = tid >> 6;          // cout-frag base
    const int l15  = lane & 15;
    const int q    = lane >> 4;
    const u32x4 zv = {0u, 0u, 0u, 0u};

    // ---- stage 3 rows x 66 cols (LDS col l <-> global x0-1+l) ----
    const int lstart = (x0 == 0) ? 1 : 0;
    const int lzero  = (x0 == 0) ? 0 : 65;
    for (int dy = 0; dy < 3; ++dy) {
        int yy = y + dy - 1;
        char* dstrow = smem + dy * ROWB;
        if (yy >= 0 && yy < H_DIM) {
            const char* src = (const char*)(in +
                ((size_t)(b * H_DIM + yy) * W_DIM + (x0 - 1 + lstart)) * 64);
            for (int i = tid * 16; i < 65 * 128; i += 256 * 16)
                *(u32x4*)(dstrow + lstart * 128 + i) = *(const u32x4*)(src + i);
            if (tid < 8)
                *(u32x4*)(dstrow + lzero * 128 + tid * 16) = zv;
        } else {
            for (int i = tid * 16; i < 66 * 128; i += 256 * 16)
                *(u32x4*)(dstrow + i) = zv;
        }
    }
    __syncthreads();

    // ---- conv3: wave w -> cf {w, w+4, w+8, w+12} (cf<14), all 64 px ----
    f32x4 acc[4][4];   // [pf][cfi]
#pragma unroll
    for (int pf = 0; pf < 4; ++pf)
#pragma unroll
        for (int cfi = 0; cfi < 4; ++cfi)
            acc[pf][cfi] = (f32x4){0.f, 0.f, 0.f, 0.f};

#pragma unroll
    for (int ks = 0; ks < 18; ++ks) {
        const int t   = ks >> 1;
        const int ci0 = (ks & 1) * 32;
        const int dy = t / 3, dx = t % 3;
        bf16x8 a[4];
#pragma unroll
        for (int pf = 0; pf < 4; ++pf) {
            const int l = pf * 16 + l15 + dx;
            const int upos = ((ci0 >> 3) + q) ^ (l & 7);
            a[pf] = *(const bf16x8*)(smem + dy * ROWB + (l * 64 + upos * 8) * 2);
        }
#pragma unroll
        for (int cfi = 0; cfi < 4; ++cfi) {
            const int cf = wave + cfi * 4;
            if (cfi < 3 || wave < 2) {            // cf < 14 (wave-uniform)
                bf16x8 wfr = *(const bf16x8*)(wpk3 + ((size_t)(ks * 14 + cf) * 64 + lane) * 8);
#pragma unroll
                for (int pf = 0; pf < 4; ++pf)
                    acc[pf][cfi] = __builtin_amdgcn_mfma_f32_16x16x32_bf16(
                        a[pf], wfr, acc[pf][cfi], 0, 0, 0);
            }
        }
    }
    __syncthreads();   // staging dead; om region aliases it

    // ---- om slices -> LDS bf16 [216][72] (wave w writes its cf rows) ----
#pragma unroll
    for (int cfi = 0; cfi < 4; ++cfi) {
        const int cf = wave + cfi * 4;
        if (cfi < 3 || wave < 2) {
            const int co = cf * 16 + l15;
            const float bv = (co < 216) ? bom[co] : 0.f;
            if (co < 216) {
#pragma unroll
                for (int pf = 0; pf < 4; ++pf)
#pragma unroll
                    for (int r = 0; r < 4; ++r) {
                        int xl = pf * 16 + q * 4 + r;
                        om_lds[co * 72 + xl] = f2bf(acc[pf][cfi][r] + bv);
                    }
            }
        }
    }
    __syncthreads();

    // ---- dump LDS -> global, 16B coalesced ----
    unsigned short* dst = omg + (size_t)b * 216 * HW + y * W_DIM + x0;
    for (int i = tid; i < 216 * 8; i += 256) {
        int row = i >> 3;
        int seg = i & 7;
        u32x4 v = *(const u32x4*)(om_lds + row * 72 + seg * 8);
        *(u32x4*)(dst + (size_t)row * HW + seg * 8) = v;
    }
}

// ---------------------------------------------------------------------------
// Modulated deformable conv, implicit GEMM (R7 shape: 64-px blocks, 4 waves
// x 16 px, full 18-ks per wave) + three latency/L2 fixes:
//  1. ALL 54 om values prefetched upfront (static addresses) -> the per-ks
//     chain starts at register-resident offsets; gather addrs computable
//     early so the compiler can keep many gathers in flight.
//  2. om loads + out stores nontemporal (touch-once streams; keep the
//     72x-reused nbrh resident in L2).
//  3. XCD-aware bijective swizzle (1024%8==0): each XCD works a contiguous
//     half-batch -> its nbrh slice stays in its private L2.
// ---------------------------------------------------------------------------
__global__ __launch_bounds__(256, 4)
void deform_mfma_kernel(const unsigned short* __restrict__ xh,  // nbr [B][HW][64] bf16
                        const unsigned short* __restrict__ omg, // bf16 [B][216][HW]
                        const unsigned short* __restrict__ wpkD,// [18][4][64][8]
                        const float* __restrict__ bdcn,
                        float* __restrict__ out)
{
    // XCD swizzle: hw-consecutive ids round-robin the 8 XCDs; remap so each
    // XCD gets a contiguous rb chunk.
    const int hwid = blockIdx.x;
    const int rb   = (hwid & 7) * (BATCH * H_DIM * 2 / 8) + (hwid >> 3);

    const int x0   = (rb & 1) * 64;
    const int y    = (rb >> 1) & 127;
    const int b    = rb >> 8;
    const int tid  = threadIdx.x;
    const int lane = tid & 63;
    const int wave = tid >> 6;
    const int l15  = lane & 15;
    const int q    = lane >> 4;
    const int px0w = wave * 16;

    const unsigned short* xb  = xh + (size_t)b * HW * 64;
    const unsigned short* omb = omg + (size_t)b * 216 * HW;
    const int x   = x0 + px0w + l15;
    const int pix = y * W_DIM + x;

    // ---- prefetch all om values (nontemporal, static addresses) ----
    float offy[18], offx[18], mk[18];
#pragma unroll
    for (int ks = 0; ks < 18; ++ks) {
        const int och = ((ks & 1) * 4 + q) * 9 + (ks >> 1);
        offy[ks] = bf2f(__builtin_nontemporal_load(omb + (size_t)och * HW + pix));
        offx[ks] = bf2f(__builtin_nontemporal_load(omb + (size_t)(72 + och) * HW + pix));
        mk[ks]   = bf2f(__builtin_nontemporal_load(omb + (size_t)(144 + och) * HW + pix));
    }
#pragma unroll
    for (int ks = 0; ks < 18; ++ks)
        mk[ks] = 1.f / (1.f + __expf(-mk[ks]));

    f32x4 acc2[4];
#pragma unroll
    for (int cf = 0; cf < 4; ++cf)
        acc2[cf] = (f32x4){0.f, 0.f, 0.f, 0.f};

#pragma unroll
    for (int ks = 0; ks < 18; ++ks) {
        const int tap = ks >> 1;
        const int g   = (ks & 1) * 4 + q;
        const int dy  = tap / 3 - 1;
        const int dx  = tap % 3 - 1;

        const float sy = offy[ks] + (float)(dy + y);
        const float sx = offx[ks] + (float)(dx + x);
        const float fy = floorf(sy);
        const float fx = floorf(sx);
        const int y0 = (int)fy;
        const int xq0 = (int)fx;
        const float ay = sy - fy;
        const float ax = sx - fx;

        const bool vy0 = (y0 >= 0) && (y0 < H_DIM);
        const bool vy1 = (y0 >= -1) && (y0 < H_DIM - 1);
        const bool vx0 = (xq0 >= 0) && (xq0 < W_DIM);
        const bool vx1 = (xq0 >= -1) && (xq0 < W_DIM - 1);

        float w00 = (1.f - ay) * (1.f - ax); if (!(vy0 && vx0)) w00 = 0.f;
        float w01 = (1.f - ay) * ax;         if (!(vy0 && vx1)) w01 = 0.f;
        float w10 = ay * (1.f - ax);         if (!(vy1 && vx0)) w10 = 0.f;
        float w11 = ay * ax;                 if (!(vy1 && vx1)) w11 = 0.f;
        const float m = mk[ks];
        w00 *= m; w01 *= m; w10 *= m; w11 *= m;

        const int iy0 = min(max(y0, 0), H_DIM - 1);
        const int iy1 = min(max(y0 + 1, 0), H_DIM - 1);
        const int ix0 = min(max(xq0, 0), W_DIM - 1);
        const int ix1 = min(max(xq0 + 1, 0), W_DIM - 1);

        const unsigned short* gb = xb + g * 8;
        const bf16x8 c00 = *(const bf16x8*)(gb + (size_t)(iy0 * W_DIM + ix0) * 64);
        const bf16x8 c01 = *(const bf16x8*)(gb + (size_t)(iy0 * W_DIM + ix1) * 64);
        const bf16x8 c10 = *(const bf16x8*)(gb + (size_t)(iy1 * W_DIM + ix0) * 64);
        const bf16x8 c11 = *(const bf16x8*)(gb + (size_t)(iy1 * W_DIM + ix1) * 64);

        bf16x8 av;
#pragma unroll
        for (int j = 0; j < 8; ++j) {
            float v = w00 * bf2f((unsigned short)c00[j])
                    + w01 * bf2f((unsigned short)c01[j])
                    + w10 * bf2f((unsigned short)c10[j])
                    + w11 * bf2f((unsigned short)c11[j]);
            av[j] = (short)f2bf(v);
        }

#pragma unroll
        for (int cf = 0; cf < 4; ++cf) {
            bf16x8 wfr = *(const bf16x8*)(wpkD + ((size_t)(ks * 4 + cf) * 64 + lane) * 8);
            acc2[cf] = __builtin_amdgcn_mfma_f32_16x16x32_bf16(av, wfr, acc2[cf], 0, 0, 0);
        }
    }

#pragma unroll
    for (int cf = 0; cf < 4; ++cf) {
        const int co = cf * 16 + l15;
        const float bv = bdcn[co];
#pragma unroll
        for (int r = 0; r < 4; ++r) {
            int xs = x0 + px0w + q * 4 + r;
            __builtin_nontemporal_store(acc2[cf][r] + bv,
                out + (size_t)(b * 64 + co) * HW + y * W_DIM + xs);
        }
    }
}

// ---------------------------------------------------------------------------
// Launcher. Workspace (bytes):
//   [0, 16.8M)        in1 swizzled-NHWC bf16
//   [16.8M, 25.2M)    c1o
//   [25.2M, 33.6M)    c2o
//   [33.6M, 42.0M)    nbrh bf16-NHWC
//   [42.0M, 70.3M)    omg bf16 [B][216][HW] (28.3M)
//   [70.3M, ...)      wpk1, wpk2, wpk3, wpkD
// ---------------------------------------------------------------------------
extern "C" void kernel_launch(void* const* d_in, const int* in_sizes, int n_in,
                              void* d_out, int out_size, void* d_ws, size_t ws_size,
                              hipStream_t stream) {
    const float* nbr  = (const float*)d_in[0];
    const float* ref  = (const float*)d_in[1];
    const float* w1   = (const float*)d_in[2];
    const float* b1   = (const float*)d_in[3];
    const float* w2   = (const float*)d_in[4];
    const float* b2   = (const float*)d_in[5];
    const float* wom  = (const float*)d_in[6];
    const float* bom  = (const float*)d_in[7];
    const float* wdcn = (const float*)d_in[8];
    const float* bdcn = (const float*)d_in[9];
    float* out = (float*)d_out;
    char* W = (char*)d_ws;

    unsigned short* in1  = (unsigned short*)(W + 0);
    unsigned short* c1o  = (unsigned short*)(W + 16777216);
    unsigned short* c2o  = (unsigned short*)(W + 25165824);
    unsigned short* nbrh = (unsigned short*)(W + 33554432);
    unsigned short* omg  = (unsigned short*)(W + 41943040);
    unsigned short* wpk1 = (unsigned short*)(W + 70254592);
    unsigned short* wpk2 = (unsigned short*)(W + 70402048);
    unsigned short* wpk3 = (unsigned short*)(W + 70475776);
    unsigned short* wpkD = (unsigned short*)(W + 70733824);

    prep_nhwc_kernel<<<dim3(HW / 64, BATCH), 256, 0, stream>>>(nbr, ref, in1);
    pack_w_kernel<<<288, 256, 0, stream>>>(w1, wpk1, 64, 128, 4, 36);
    pack_w_kernel<<<144, 256, 0, stream>>>(w2, wpk2, 64, 64, 4, 18);
    pack_w_kernel<<<504, 256, 0, stream>>>(wom, wpk3, 216, 64, 14, 18);
    pack_w_kernel<<<144, 256, 0, stream>>>(wdcn, wpkD, 64, 64, 4, 18);
    prep_nbr_nhwc_kernel<<<dim3(HW / 64, BATCH), 256, 0, stream>>>(nbr, nbrh);

    // conv1: concat(nbr,ref) 128ch -> 64, lrelu
    conv_mfma_kernel<128, 36, true>
        <<<dim3(BATCH * H_DIM), 256, 0, stream>>>(in1, wpk1, b1, c1o);
    // conv2: 64 -> 64, lrelu
    conv_mfma_kernel<64, 18, true>
        <<<dim3(BATCH * H_DIM), 256, 0, stream>>>(c1o, wpk2, b2, c2o);

    // conv3 -> om bf16 global (coalesced, cout-split waves)
    conv3om_kernel<<<dim3(BATCH * H_DIM * 2), 256, 0, stream>>>(
        c2o, wpk3, bom, omg);
    // deformable conv (om prefetch + nt streams + XCD swizzle)
    deform_mfma_kernel<<<dim3(BATCH * H_DIM * 2), 256, 0, stream>>>(
        nbrh, omg, wpkD, bdcn, out);
}

// Round 11
// 134.500 us; speedup vs baseline: 1.2886x; 1.1120x over previous
//
#include <hip/hip_runtime.h>
#include <hip/hip_bf16.h>
#include <math.h>

#define H_DIM 128
#define W_DIM 128
#define BATCH 4
#define HW (H_DIM * W_DIM)

typedef __attribute__((ext_vector_type(8))) short bf16x8;
typedef __attribute__((ext_vector_type(4))) float f32x4;
typedef __attribute__((ext_vector_type(4))) unsigned int u32x4;

static __device__ __forceinline__ unsigned short f2bf(float f) {
    __hip_bfloat16 h = __float2bfloat16(f);   // RNE
    return *reinterpret_cast<unsigned short*>(&h);
}
static __device__ __forceinline__ float bf2f(unsigned short u) {
    return __uint_as_float(((unsigned int)u) << 16);
}

// ---------------------------------------------------------------------------
// Build swizzled-NHWC bf16 concat input [B][H][W][128] via LDS transpose.
// Swizzle: true channel-unit ut (8 bf16 = 16B) of column x stored at unit
// position (ut&8) | ((ut&7) ^ ((x+1)&7)).
// ---------------------------------------------------------------------------
__global__ __launch_bounds__(256)
void prep_nhwc_kernel(const float* __restrict__ nbr, const float* __restrict__ ref,
                      unsigned short* __restrict__ dst) {
    __shared__ float s[128][65];   // 33.3 KB
    const int b  = blockIdx.y;
    const int p0 = blockIdx.x * 64;          // aligned 64 px, same row y
    const int t  = threadIdx.x;
    const int px = t & 63;
#pragma unroll
    for (int it = 0; it < 32; ++it) {
        int c = it * 4 + (t >> 6);           // 0..127
        const float* src = (c < 64) ? nbr : ref;
        int cs = c & 63;
        s[c][px] = src[(size_t)(b * 64 + cs) * HW + p0 + px];
    }
    __syncthreads();
#pragma unroll
    for (int it = 0; it < 4; ++it) {
        int idx = it * 256 + t;              // p*16 + ut
        int p  = idx >> 4;
        int ut = idx & 15;
        int x  = (p0 + p) & 127;
        int key = (x + 1) & 7;
        int cpos = (ut & 8) | ((ut & 7) ^ key);
        bf16x8 v;
#pragma unroll
        for (int j = 0; j < 8; ++j)
            v[j] = (short)f2bf(s[ut * 8 + j][p]);
        *(bf16x8*)(dst + ((size_t)(b * HW + p0 + p) * 128 + cpos * 8)) = v;
    }
}

// ---------------------------------------------------------------------------
// Group-major bf16 copy of nbr: [B][8g][HW][8ch]. Adjacent pixels of the
// same deformable group are 16B apart -> deform gathers from lanes with
// smooth offsets coalesce into few 64B sectors (the R9 layout had each lane
// in its own sector: 4x L2 transaction amplification).
// ---------------------------------------------------------------------------
__global__ __launch_bounds__(256)
void prep_nbr_gmajor_kernel(const float* __restrict__ nbr,
                            unsigned short* __restrict__ dst) {
    __shared__ float s[64][65];
    const int b  = blockIdx.y;
    const int p0 = blockIdx.x * 64;
    const int t  = threadIdx.x;
#pragma unroll
    for (int it = 0; it < 16; ++it) {
        int c = it * 4 + (t >> 6);
        s[c][t & 63] = nbr[(size_t)(b * 64 + c) * HW + p0 + (t & 63)];
    }
    __syncthreads();
#pragma unroll
    for (int it = 0; it < 2; ++it) {
        int idx = it * 256 + t;       // g*64 + px  (px fastest -> coalesced)
        int g  = idx >> 6;
        int px = idx & 63;
        bf16x8 v;
#pragma unroll
        for (int j = 0; j < 8; ++j)
            v[j] = (short)f2bf(s[g * 8 + j][px]);
        *(bf16x8*)(dst + ((size_t)(b * 8 + g) * HW + p0 + px) * 8) = v;
    }
}

// ---------------------------------------------------------------------------
// Pack conv weights [COUT][CIN][3][3] fp32 -> MFMA B-fragment order bf16.
// ---------------------------------------------------------------------------
__global__ void pack_w_kernel(const float* __restrict__ w, unsigned short* __restrict__ dst,
                              int COUT_real, int CIN, int NCF, int NKS) {
    int idx = blockIdx.x * 256 + threadIdx.x;
    int total = NKS * NCF * 64 * 8;
    if (idx >= total) return;
    int j    = idx & 7;
    int lane = (idx >> 3) & 63;
    int frag = idx >> 9;
    int cf   = frag % NCF;
    int ks   = frag / NCF;
    int co = cf * 16 + (lane & 15);
    int k  = ks * 32 + (lane >> 4) * 8 + j;
    int t  = k / CIN;
    int ci = k % CIN;
    float v = (co < COUT_real) ? w[((size_t)co * CIN + ci) * 9 + t] : 0.f;
    dst[idx] = f2bf(v);
}

// ---------------------------------------------------------------------------
// Implicit-GEMM 3x3 SAME conv via bf16 MFMA (conv1 / conv2).
// ---------------------------------------------------------------------------
template<int CIN, int NKS, bool RELU>
__global__ __launch_bounds__(256)
void conv_mfma_kernel(const unsigned short* __restrict__ in,   // swizzled NHWC bf16
                      const unsigned short* __restrict__ wpk,  // packed weight frags
                      const float* __restrict__ bias,
                      unsigned short* __restrict__ out)
{
    static_assert(CIN % 32 == 0, "CIN must be multiple of 32");
    constexpr int ROWB = 132 * CIN * 2;      // bytes per dy row in LDS
    __shared__ __align__(16) char smem[3 * ROWB];

    const int rb  = blockIdx.x;        // b*H + y
    const int b   = rb >> 7;
    const int y   = rb & 127;
    const int tid  = threadIdx.x;
    const int lane = tid & 63;
    const int wave = tid >> 6;
    const int l15  = lane & 15;
    const int q    = lane >> 4;
    const u32x4 zv = {0u, 0u, 0u, 0u};

    for (int dy = 0; dy < 3; ++dy) {
        int yy = y + dy - 1;
        char* dstrow = smem + dy * ROWB;
        if (yy >= 0 && yy < H_DIM) {
            const char* src = (const char*)(in + ((size_t)(b * H_DIM + yy) * W_DIM) * CIN);
            for (int i = tid * 16; i < 128 * CIN * 2; i += 256 * 16)
                *(u32x4*)(dstrow + CIN * 2 + i) = *(const u32x4*)(src + i);
            for (int i = tid; i < 2 * (CIN / 8); i += 256) {
                int col = (i < CIN / 8) ? 0 : 129;
                int u   = i % (CIN / 8);
                *(u32x4*)(dstrow + (col * CIN + u * 8) * 2) = zv;
            }
        } else {
            for (int i = tid * 16; i < 130 * CIN * 2; i += 256 * 16)
                *(u32x4*)(dstrow + i) = zv;
        }
    }
    __syncthreads();

    f32x4 acc[2][4];
#pragma unroll
    for (int pf = 0; pf < 2; ++pf)
#pragma unroll
        for (int cf = 0; cf < 4; ++cf)
            acc[pf][cf] = (f32x4){0.f, 0.f, 0.f, 0.f};

    const int px0 = wave * 32;
#pragma unroll
    for (int ks = 0; ks < NKS; ++ks) {
        const int t   = ks / (CIN / 32);
        const int ci0 = (ks % (CIN / 32)) * 32;
        const int dy = t / 3, dx = t % 3;
        bf16x8 a[2];
#pragma unroll
        for (int pf = 0; pf < 2; ++pf) {
            int gx = px0 + pf * 16 + l15 + dx;
            int upos = ((ci0 >> 3) + q) ^ (gx & 7);
            a[pf] = *(const bf16x8*)(smem + dy * ROWB + (gx * CIN + upos * 8) * 2);
        }
        bf16x8 wfr[4];
#pragma unroll
        for (int cf = 0; cf < 4; ++cf)
            wfr[cf] = *(const bf16x8*)(wpk + ((size_t)(ks * 4 + cf) * 64 + lane) * 8);
#pragma unroll
        for (int pf = 0; pf < 2; ++pf)
#pragma unroll
            for (int cf = 0; cf < 4; ++cf)
                acc[pf][cf] = __builtin_amdgcn_mfma_f32_16x16x32_bf16(
                    a[pf], wfr[cf], acc[pf][cf], 0, 0, 0);
    }

#pragma unroll
    for (int pf = 0; pf < 2; ++pf)
#pragma unroll
        for (int cf = 0; cf < 4; ++cf) {
            const int co = cf * 16 + l15;
            const float bv = bias[co];
#pragma unroll
            for (int r = 0; r < 4; ++r) {
                int x = px0 + pf * 16 + q * 4 + r;
                float v = acc[pf][cf][r] + bv;
                if (RELU) v = (v >= 0.f) ? v : 0.1f * v;
                int cpos = (((co >> 3) ^ ((x + 1) & 7)) << 3) | (co & 7);
                out[((size_t)(b * H_DIM + y) * W_DIM + x) * 64 + cpos] = f2bf(v);
            }
        }
}

// ---------------------------------------------------------------------------
// conv3 (216 couts) -> om bf16 [B][216][HW] global, coalesced via LDS.
// Block = (b, y, half): 64 pixels, 4 waves; waves split couts (R7).
// ---------------------------------------------------------------------------
__global__ __launch_bounds__(256, 4)
void conv3om_kernel(const unsigned short* __restrict__ in,   // c2o swizzled NHWC
                    const unsigned short* __restrict__ wpk3, // [18][14][64][8]
                    const float* __restrict__ bom,
                    unsigned short* __restrict__ omg)        // bf16 [B][216][HW]
{
    constexpr int ROWB = 66 * 128;                 // staging bytes per dy row
    __shared__ __align__(16) char smem[216 * 72 * 2];   // 31104 B union
    unsigned short* om_lds = (unsigned short*)smem;

    const int rb   = blockIdx.x;        // ((b*H + y)<<1) | half
    const int x0   = (rb & 1) * 64;
    const int y    = (rb >> 1) & 127;
    const int b    = rb >> 8;
    const int tid  = threadIdx.x;
    const int lane = tid & 63;
    const int wave = tid >> 6;          // cout-frag base
    const int l15  = lane & 15;
    const int q    = lane >> 4;
    const u32x4 zv = {0u, 0u, 0u, 0u};

    // ---- stage 3 rows x 66 cols (LDS col l <-> global x0-1+l) ----
    const int lstart = (x0 == 0) ? 1 : 0;
    const int lzero  = (x0 == 0) ? 0 : 65;
    for (int dy = 0; dy < 3; ++dy) {
        int yy = y + dy - 1;
        char* dstrow = smem + dy * ROWB;
        if (yy >= 0 && yy < H_DIM) {
            const char* src = (const char*)(in +
                ((size_t)(b * H_DIM + yy) * W_DIM + (x0 - 1 + lstart)) * 64);
            for (int i = tid * 16; i < 65 * 128; i += 256 * 16)
                *(u32x4*)(dstrow + lstart * 128 + i) = *(const u32x4*)(src + i);
            if (tid < 8)
                *(u32x4*)(dstrow + lzero * 128 + tid * 16) = zv;
        } else {
            for (int i = tid * 16; i < 66 * 128; i += 256 * 16)
                *(u32x4*)(dstrow + i) = zv;
        }
    }
    __syncthreads();

    // ---- conv3: wave w -> cf {w, w+4, w+8, w+12} (cf<14), all 64 px ----
    f32x4 acc[4][4];   // [pf][cfi]
#pragma unroll
    for (int pf = 0; pf < 4; ++pf)
#pragma unroll
        for (int cfi = 0; cfi < 4; ++cfi)
            acc[pf][cfi] = (f32x4){0.f, 0.f, 0.f, 0.f};

#pragma unroll
    for (int ks = 0; ks < 18; ++ks) {
        const int t   = ks >> 1;
        const int ci0 = (ks & 1) * 32;
        const int dy = t / 3, dx = t % 3;
        bf16x8 a[4];
#pragma unroll
        for (int pf = 0; pf < 4; ++pf) {
            const int l = pf * 16 + l15 + dx;
            const int upos = ((ci0 >> 3) + q) ^ (l & 7);
            a[pf] = *(const bf16x8*)(smem + dy * ROWB + (l * 64 + upos * 8) * 2);
        }
#pragma unroll
        for (int cfi = 0; cfi < 4; ++cfi) {
            const int cf = wave + cfi * 4;
            if (cfi < 3 || wave < 2) {            // cf < 14 (wave-uniform)
                bf16x8 wfr = *(const bf16x8*)(wpk3 + ((size_t)(ks * 14 + cf) * 64 + lane) * 8);
#pragma unroll
                for (int pf = 0; pf < 4; ++pf)
                    acc[pf][cfi] = __builtin_amdgcn_mfma_f32_16x16x32_bf16(
                        a[pf], wfr, acc[pf][cfi], 0, 0, 0);
            }
        }
    }
    __syncthreads();   // staging dead; om region aliases it

    // ---- om slices -> LDS bf16 [216][72] (wave w writes its cf rows) ----
#pragma unroll
    for (int cfi = 0; cfi < 4; ++cfi) {
        const int cf = wave + cfi * 4;
        if (cfi < 3 || wave < 2) {
            const int co = cf * 16 + l15;
            const float bv = (co < 216) ? bom[co] : 0.f;
            if (co < 216) {
#pragma unroll
                for (int pf = 0; pf < 4; ++pf)
#pragma unroll
                    for (int r = 0; r < 4; ++r) {
                        int xl = pf * 16 + q * 4 + r;
                        om_lds[co * 72 + xl] = f2bf(acc[pf][cfi][r] + bv);
                    }
            }
        }
    }
    __syncthreads();

    // ---- dump LDS -> global, 16B coalesced ----
    unsigned short* dst = omg + (size_t)b * 216 * HW + y * W_DIM + x0;
    for (int i = tid; i < 216 * 8; i += 256) {
        int row = i >> 3;
        int seg = i & 7;
        u32x4 v = *(const u32x4*)(om_lds + row * 72 + seg * 8);
        *(u32x4*)(dst + (size_t)row * HW + seg * 8) = v;
    }
}

// ---------------------------------------------------------------------------
// Modulated deformable conv, implicit GEMM. R9 structure (om prefetch, nt
// streams, XCD swizzle) with GROUP-MAJOR x layout [B][8g][HW][8ch]: adjacent
// lanes of a q-group gather adjacent 16B chunks -> few 64B L2 sectors.
// ---------------------------------------------------------------------------
__global__ __launch_bounds__(256, 4)
void deform_mfma_kernel(const unsigned short* __restrict__ xg,  // [B][8][HW][8] bf16
                        const unsigned short* __restrict__ omg, // bf16 [B][216][HW]
                        const unsigned short* __restrict__ wpkD,// [18][4][64][8]
                        const float* __restrict__ bdcn,
                        float* __restrict__ out)
{
    const int hwid = blockIdx.x;
    const int rb   = (hwid & 7) * (BATCH * H_DIM * 2 / 8) + (hwid >> 3);

    const int x0   = (rb & 1) * 64;
    const int y    = (rb >> 1) & 127;
    const int b    = rb >> 8;
    const int tid  = threadIdx.x;
    const int lane = tid & 63;
    const int wave = tid >> 6;
    const int l15  = lane & 15;
    const int q    = lane >> 4;
    const int px0w = wave * 16;

    const unsigned short* omb = omg + (size_t)b * 216 * HW;
    const int x   = x0 + px0w + l15;
    const int pix = y * W_DIM + x;

    // ---- prefetch all om values (nontemporal, static addresses) ----
    float offy[18], offx[18], mk[18];
#pragma unroll
    for (int ks = 0; ks < 18; ++ks) {
        const int och = ((ks & 1) * 4 + q) * 9 + (ks >> 1);
        offy[ks] = bf2f(__builtin_nontemporal_load(omb + (size_t)och * HW + pix));
        offx[ks] = bf2f(__builtin_nontemporal_load(omb + (size_t)(72 + och) * HW + pix));
        mk[ks]   = bf2f(__builtin_nontemporal_load(omb + (size_t)(144 + och) * HW + pix));
    }
#pragma unroll
    for (int ks = 0; ks < 18; ++ks)
        mk[ks] = 1.f / (1.f + __expf(-mk[ks]));

    f32x4 acc2[4];
#pragma unroll
    for (int cf = 0; cf < 4; ++cf)
        acc2[cf] = (f32x4){0.f, 0.f, 0.f, 0.f};

#pragma unroll
    for (int ks = 0; ks < 18; ++ks) {
        const int tap = ks >> 1;
        const int g   = (ks & 1) * 4 + q;
        const int dy  = tap / 3 - 1;
        const int dx  = tap % 3 - 1;

        const float sy = offy[ks] + (float)(dy + y);
        const float sx = offx[ks] + (float)(dx + x);
        const float fy = floorf(sy);
        const float fx = floorf(sx);
        const int y0 = (int)fy;
        const int xq0 = (int)fx;
        const float ay = sy - fy;
        const float ax = sx - fx;

        const bool vy0 = (y0 >= 0) && (y0 < H_DIM);
        const bool vy1 = (y0 >= -1) && (y0 < H_DIM - 1);
        const bool vx0 = (xq0 >= 0) && (xq0 < W_DIM);
        const bool vx1 = (xq0 >= -1) && (xq0 < W_DIM - 1);

        float w00 = (1.f - ay) * (1.f - ax); if (!(vy0 && vx0)) w00 = 0.f;
        float w01 = (1.f - ay) * ax;         if (!(vy0 && vx1)) w01 = 0.f;
        float w10 = ay * (1.f - ax);         if (!(vy1 && vx0)) w10 = 0.f;
        float w11 = ay * ax;                 if (!(vy1 && vx1)) w11 = 0.f;
        const float m = mk[ks];
        w00 *= m; w01 *= m; w10 *= m; w11 *= m;

        const int iy0 = min(max(y0, 0), H_DIM - 1);
        const int iy1 = min(max(y0 + 1, 0), H_DIM - 1);
        const int ix0 = min(max(xq0, 0), W_DIM - 1);
        const int ix1 = min(max(xq0 + 1, 0), W_DIM - 1);

        const unsigned short* gb = xg + (size_t)(b * 8 + g) * HW * 8;
        const bf16x8 c00 = *(const bf16x8*)(gb + (size_t)(iy0 * W_DIM + ix0) * 8);
        const bf16x8 c01 = *(const bf16x8*)(gb + (size_t)(iy0 * W_DIM + ix1) * 8);
        const bf16x8 c10 = *(const bf16x8*)(gb + (size_t)(iy1 * W_DIM + ix0) * 8);
        const bf16x8 c11 = *(const bf16x8*)(gb + (size_t)(iy1 * W_DIM + ix1) * 8);

        bf16x8 av;
#pragma unroll
        for (int j = 0; j < 8; ++j) {
            float v = w00 * bf2f((unsigned short)c00[j])
                    + w01 * bf2f((unsigned short)c01[j])
                    + w10 * bf2f((unsigned short)c10[j])
                    + w11 * bf2f((unsigned short)c11[j]);
            av[j] = (short)f2bf(v);
        }

#pragma unroll
        for (int cf = 0; cf < 4; ++cf) {
            bf16x8 wfr = *(const bf16x8*)(wpkD + ((size_t)(ks * 4 + cf) * 64 + lane) * 8);
            acc2[cf] = __builtin_amdgcn_mfma_f32_16x16x32_bf16(av, wfr, acc2[cf], 0, 0, 0);
        }
    }

#pragma unroll
    for (int cf = 0; cf < 4; ++cf) {
        const int co = cf * 16 + l15;
        const float bv = bdcn[co];
#pragma unroll
        for (int r = 0; r < 4; ++r) {
            int xs = x0 + px0w + q * 4 + r;
            __builtin_nontemporal_store(acc2[cf][r] + bv,
                out + (size_t)(b * 64 + co) * HW + y * W_DIM + xs);
        }
    }
}

// ---------------------------------------------------------------------------
// Launcher. Workspace (bytes):
//   [0, 16.8M)        in1 swizzled-NHWC bf16
//   [16.8M, 25.2M)    c1o
//   [25.2M, 33.6M)    c2o
//   [33.6M, 42.0M)    nbrg bf16 group-major [B][8][HW][8]
//   [42.0M, 70.3M)    omg bf16 [B][216][HW] (28.3M)
//   [70.3M, ...)      wpk1, wpk2, wpk3, wpkD
// ---------------------------------------------------------------------------
extern "C" void kernel_launch(void* const* d_in, const int* in_sizes, int n_in,
                              void* d_out, int out_size, void* d_ws, size_t ws_size,
                              hipStream_t stream) {
    const float* nbr  = (const float*)d_in[0];
    const float* ref  = (const float*)d_in[1];
    const float* w1   = (const float*)d_in[2];
    const float* b1   = (const float*)d_in[3];
    const float* w2   = (const float*)d_in[4];
    const float* b2   = (const float*)d_in[5];
    const float* wom  = (const float*)d_in[6];
    const float* bom  = (const float*)d_in[7];
    const float* wdcn = (const float*)d_in[8];
    const float* bdcn = (const float*)d_in[9];
    float* out = (float*)d_out;
    char* W = (char*)d_ws;

    unsigned short* in1  = (unsigned short*)(W + 0);
    unsigned short* c1o  = (unsigned short*)(W + 16777216);
    unsigned short* c2o  = (unsigned short*)(W + 25165824);
    unsigned short* nbrg = (unsigned short*)(W + 33554432);
    unsigned short* omg  = (unsigned short*)(W + 41943040);
    unsigned short* wpk1 = (unsigned short*)(W + 70254592);
    unsigned short* wpk2 = (unsigned short*)(W + 70402048);
    unsigned short* wpk3 = (unsigned short*)(W + 70475776);
    unsigned short* wpkD = (unsigned short*)(W + 70733824);

    prep_nhwc_kernel<<<dim3(HW / 64, BATCH), 256, 0, stream>>>(nbr, ref, in1);
    pack_w_kernel<<<288, 256, 0, stream>>>(w1, wpk1, 64, 128, 4, 36);
    pack_w_kernel<<<144, 256, 0, stream>>>(w2, wpk2, 64, 64, 4, 18);
    pack_w_kernel<<<504, 256, 0, stream>>>(wom, wpk3, 216, 64, 14, 18);
    pack_w_kernel<<<144, 256, 0, stream>>>(wdcn, wpkD, 64, 64, 4, 18);
    prep_nbr_gmajor_kernel<<<dim3(HW / 64, BATCH), 256, 0, stream>>>(nbr, nbrg);

    // conv1: concat(nbr,ref) 128ch -> 64, lrelu
    conv_mfma_kernel<128, 36, true>
        <<<dim3(BATCH * H_DIM), 256, 0, stream>>>(in1, wpk1, b1, c1o);
    // conv2: 64 -> 64, lrelu
    conv_mfma_kernel<64, 18, true>
        <<<dim3(BATCH * H_DIM), 256, 0, stream>>>(c1o, wpk2, b2, c2o);

    // conv3 -> om bf16 global (coalesced, cout-split waves)
    conv3om_kernel<<<dim3(BATCH * H_DIM * 2), 256, 0, stream>>>(
        c2o, wpk3, bom, omg);
    // deformable conv (group-major gathers + om prefetch + nt + XCD swizzle)
    deform_mfma_kernel<<<dim3(BATCH * H_DIM * 2), 256, 0, stream>>>(
        nbrg, omg, wpkD, bdcn, out);
}

// Round 12
// 121.831 us; speedup vs baseline: 1.4226x; 1.1040x over previous
//
#include <hip/hip_runtime.h>
#include <hip/hip_bf16.h>
#include <math.h>

#define H_DIM 128
#define W_DIM 128
#define BATCH 4
#define HW (H_DIM * W_DIM)

typedef __attribute__((ext_vector_type(8))) short bf16x8;
typedef __attribute__((ext_vector_type(4))) float f32x4;
typedef __attribute__((ext_vector_type(4))) unsigned int u32x4;

static __device__ __forceinline__ unsigned short f2bf(float f) {
    __hip_bfloat16 h = __float2bfloat16(f);   // RNE
    return *reinterpret_cast<unsigned short*>(&h);
}
static __device__ __forceinline__ float bf2f(unsigned short u) {
    return __uint_as_float(((unsigned int)u) << 16);
}

// ---------------------------------------------------------------------------
// Build swizzled-NHWC bf16 concat input [B][H][W][128]  AND  group-major
// nbr copy [B][8g][HW][8ch] in one pass (nbr already staged in LDS).
// Swizzle: unit ut of column x stored at (ut&8) | ((ut&7) ^ ((x+1)&7)).
// ---------------------------------------------------------------------------
__global__ __launch_bounds__(256)
void prep_nhwc_kernel(const float* __restrict__ nbr, const float* __restrict__ ref,
                      unsigned short* __restrict__ dst,
                      unsigned short* __restrict__ gmaj) {
    __shared__ float s[128][65];   // 33.3 KB
    const int b  = blockIdx.y;
    const int p0 = blockIdx.x * 64;          // aligned 64 px, same row y
    const int t  = threadIdx.x;
    const int px = t & 63;
#pragma unroll
    for (int it = 0; it < 32; ++it) {
        int c = it * 4 + (t >> 6);           // 0..127
        const float* src = (c < 64) ? nbr : ref;
        int cs = c & 63;
        s[c][px] = src[(size_t)(b * 64 + cs) * HW + p0 + px];
    }
    __syncthreads();
#pragma unroll
    for (int it = 0; it < 4; ++it) {
        int idx = it * 256 + t;              // p*16 + ut
        int p  = idx >> 4;
        int ut = idx & 15;
        int x  = (p0 + p) & 127;
        int key = (x + 1) & 7;
        int cpos = (ut & 8) | ((ut & 7) ^ key);
        bf16x8 v;
#pragma unroll
        for (int j = 0; j < 8; ++j)
            v[j] = (short)f2bf(s[ut * 8 + j][p]);
        *(bf16x8*)(dst + ((size_t)(b * HW + p0 + p) * 128 + cpos * 8)) = v;
    }
    // group-major nbr output (channels 0..63 of s)
#pragma unroll
    for (int it = 0; it < 2; ++it) {
        int idx = it * 256 + t;       // g*64 + px (px fastest -> coalesced)
        int g   = idx >> 6;
        int p2  = idx & 63;
        bf16x8 v;
#pragma unroll
        for (int j = 0; j < 8; ++j)
            v[j] = (short)f2bf(s[g * 8 + j][p2]);
        *(bf16x8*)(gmaj + ((size_t)(b * 8 + g) * HW + p0 + p2) * 8) = v;
    }
}

// ---------------------------------------------------------------------------
// Pack conv weights [COUT][CIN][3][3] fp32 -> MFMA B-fragment order bf16.
// ---------------------------------------------------------------------------
__global__ void pack_w_kernel(const float* __restrict__ w, unsigned short* __restrict__ dst,
                              int COUT_real, int CIN, int NCF, int NKS) {
    int idx = blockIdx.x * 256 + threadIdx.x;
    int total = NKS * NCF * 64 * 8;
    if (idx >= total) return;
    int j    = idx & 7;
    int lane = (idx >> 3) & 63;
    int frag = idx >> 9;
    int cf   = frag % NCF;
    int ks   = frag / NCF;
    int co = cf * 16 + (lane & 15);
    int k  = ks * 32 + (lane >> 4) * 8 + j;
    int t  = k / CIN;
    int ci = k % CIN;
    float v = (co < COUT_real) ? w[((size_t)co * CIN + ci) * 9 + t] : 0.f;
    dst[idx] = f2bf(v);
}

// ---------------------------------------------------------------------------
// Implicit-GEMM 3x3 conv, 64-px tiles, COUT-SPLIT waves (conv1/conv2).
// Block = (b, y, half): 64 px, 4 waves; wave w -> couts [w*16, w*16+16),
// all 64 px (4 A-frags from LDS). Per ks: 4 ds_read + 1 weight load ->
// 4 MFMA. LDS = 3*66*CIN*2 (conv1 50.7KB -> 3 blk/CU; conv2 25.3KB -> 6).
// ---------------------------------------------------------------------------
template<int CIN, int NKS, bool RELU>
__global__ __launch_bounds__(256, 3)
void conv64_mfma_kernel(const unsigned short* __restrict__ in,   // swizzled NHWC bf16
                        const unsigned short* __restrict__ wpk,  // [NKS][4][64][8]
                        const float* __restrict__ bias,
                        unsigned short* __restrict__ out)
{
    constexpr int ROWB = 66 * CIN * 2;
    __shared__ __align__(16) char smem[3 * ROWB];

    const int rb   = blockIdx.x;        // ((b*H + y)<<1) | half
    const int x0   = (rb & 1) * 64;
    const int y    = (rb >> 1) & 127;
    const int b    = rb >> 8;
    const int tid  = threadIdx.x;
    const int lane = tid & 63;
    const int wave = tid >> 6;          // cout-frag index
    const int l15  = lane & 15;
    const int q    = lane >> 4;
    const u32x4 zv = {0u, 0u, 0u, 0u};

    // ---- stage 3 rows x 66 cols (LDS col l <-> global x0-1+l) ----
    const int lstart = (x0 == 0) ? 1 : 0;
    const int lzero  = (x0 == 0) ? 0 : 65;
    for (int dy = 0; dy < 3; ++dy) {
        int yy = y + dy - 1;
        char* dstrow = smem + dy * ROWB;
        if (yy >= 0 && yy < H_DIM) {
            const char* src = (const char*)(in +
                ((size_t)(b * H_DIM + yy) * W_DIM + (x0 - 1 + lstart)) * CIN);
            for (int i = tid * 16; i < 65 * CIN * 2; i += 256 * 16)
                *(u32x4*)(dstrow + lstart * CIN * 2 + i) = *(const u32x4*)(src + i);
            if (tid < CIN / 8)
                *(u32x4*)(dstrow + lzero * CIN * 2 + tid * 16) = zv;
        } else {
            for (int i = tid * 16; i < 66 * CIN * 2; i += 256 * 16)
                *(u32x4*)(dstrow + i) = zv;
        }
    }
    __syncthreads();

    f32x4 acc[4];
#pragma unroll
    for (int pf = 0; pf < 4; ++pf)
        acc[pf] = (f32x4){0.f, 0.f, 0.f, 0.f};

#pragma unroll
    for (int ks = 0; ks < NKS; ++ks) {
        const int t   = ks / (CIN / 32);
        const int ci0 = (ks % (CIN / 32)) * 32;
        const int dy = t / 3, dx = t % 3;
        const int u  = (ci0 >> 3) + q;
        bf16x8 a[4];
#pragma unroll
        for (int pf = 0; pf < 4; ++pf) {
            const int l = pf * 16 + l15 + dx;
            const int upos = u ^ (l & 7);
            a[pf] = *(const bf16x8*)(smem + dy * ROWB + (l * CIN + upos * 8) * 2);
        }
        bf16x8 wfr = *(const bf16x8*)(wpk + ((size_t)(ks * 4 + wave) * 64 + lane) * 8);
#pragma unroll
        for (int pf = 0; pf < 4; ++pf)
            acc[pf] = __builtin_amdgcn_mfma_f32_16x16x32_bf16(a[pf], wfr, acc[pf], 0, 0, 0);
    }

    const int co = wave * 16 + l15;
    const float bv = bias[co];
#pragma unroll
    for (int pf = 0; pf < 4; ++pf)
#pragma unroll
        for (int r = 0; r < 4; ++r) {
            int x = x0 + pf * 16 + q * 4 + r;
            float v = acc[pf][r] + bv;
            if (RELU) v = (v >= 0.f) ? v : 0.1f * v;
            int cpos = (((co >> 3) ^ ((x + 1) & 7)) << 3) | (co & 7);
            out[((size_t)(b * H_DIM + y) * W_DIM + x) * 64 + cpos] = f2bf(v);
        }
}

// ---------------------------------------------------------------------------
// conv3 (216 couts) -> om bf16 [B][216][HW] global, coalesced via LDS.
// Block = (b, y, half): 64 pixels, 4 waves; waves split couts (R7). UNCHANGED.
// ---------------------------------------------------------------------------
__global__ __launch_bounds__(256, 4)
void conv3om_kernel(const unsigned short* __restrict__ in,   // c2o swizzled NHWC
                    const unsigned short* __restrict__ wpk3, // [18][14][64][8]
                    const float* __restrict__ bom,
                    unsigned short* __restrict__ omg)        // bf16 [B][216][HW]
{
    constexpr int ROWB = 66 * 128;
    __shared__ __align__(16) char smem[216 * 72 * 2];   // 31104 B union
    unsigned short* om_lds = (unsigned short*)smem;

    const int rb   = blockIdx.x;        // ((b*H + y)<<1) | half
    const int x0   = (rb & 1) * 64;
    const int y    = (rb >> 1) & 127;
    const int b    = rb >> 8;
    const int tid  = threadIdx.x;
    const int lane = tid & 63;
    const int wave = tid >> 6;
    const int l15  = lane & 15;
    const int q    = lane >> 4;
    const u32x4 zv = {0u, 0u, 0u, 0u};

    const int lstart = (x0 == 0) ? 1 : 0;
    const int lzero  = (x0 == 0) ? 0 : 65;
    for (int dy = 0; dy < 3; ++dy) {
        int yy = y + dy - 1;
        char* dstrow = smem + dy * ROWB;
        if (yy >= 0 && yy < H_DIM) {
            const char* src = (const char*)(in +
                ((size_t)(b * H_DIM + yy) * W_DIM + (x0 - 1 + lstart)) * 64);
            for (int i = tid * 16; i < 65 * 128; i += 256 * 16)
                *(u32x4*)(dstrow + lstart * 128 + i) = *(const u32x4*)(src + i);
            if (tid < 8)
                *(u32x4*)(dstrow + lzero * 128 + tid * 16) = zv;
        } else {
            for (int i = tid * 16; i < 66 * 128; i += 256 * 16)
                *(u32x4*)(dstrow + i) = zv;
        }
    }
    __syncthreads();

    f32x4 acc[4][4];   // [pf][cfi]
#pragma unroll
    for (int pf = 0; pf < 4; ++pf)
#pragma unroll
        for (int cfi = 0; cfi < 4; ++cfi)
            acc[pf][cfi] = (f32x4){0.f, 0.f, 0.f, 0.f};

#pragma unroll
    for (int ks = 0; ks < 18; ++ks) {
        const int t   = ks >> 1;
        const int ci0 = (ks & 1) * 32;
        const int dy = t / 3, dx = t % 3;
        bf16x8 a[4];
#pragma unroll
        for (int pf = 0; pf < 4; ++pf) {
            const int l = pf * 16 + l15 + dx;
            const int upos = ((ci0 >> 3) + q) ^ (l & 7);
            a[pf] = *(const bf16x8*)(smem + dy * ROWB + (l * 64 + upos * 8) * 2);
        }
#pragma unroll
        for (int cfi = 0; cfi < 4; ++cfi) {
            const int cf = wave + cfi * 4;
            if (cfi < 3 || wave < 2) {            // cf < 14 (wave-uniform)
                bf16x8 wfr = *(const bf16x8*)(wpk3 + ((size_t)(ks * 14 + cf) * 64 + lane) * 8);
#pragma unroll
                for (int pf = 0; pf < 4; ++pf)
                    acc[pf][cfi] = __builtin_amdgcn_mfma_f32_16x16x32_bf16(
                        a[pf], wfr, acc[pf][cfi], 0, 0, 0);
            }
        }
    }
    __syncthreads();

#pragma unroll
    for (int cfi = 0; cfi < 4; ++cfi) {
        const int cf = wave + cfi * 4;
        if (cfi < 3 || wave < 2) {
            const int co = cf * 16 + l15;
            const float bv = (co < 216) ? bom[co] : 0.f;
            if (co < 216) {
#pragma unroll
                for (int pf = 0; pf < 4; ++pf)
#pragma unroll
                    for (int r = 0; r < 4; ++r) {
                        int xl = pf * 16 + q * 4 + r;
                        om_lds[co * 72 + xl] = f2bf(acc[pf][cfi][r] + bv);
                    }
            }
        }
    }
    __syncthreads();

    unsigned short* dst = omg + (size_t)b * 216 * HW + y * W_DIM + x0;
    for (int i = tid; i < 216 * 8; i += 256) {
        int row = i >> 3;
        int seg = i & 7;
        u32x4 v = *(const u32x4*)(om_lds + row * 72 + seg * 8);
        *(u32x4*)(dst + (size_t)row * HW + seg * 8) = v;
    }
}

// ---------------------------------------------------------------------------
// Modulated deformable conv, implicit GEMM. Group-major x [B][8][HW][8],
// nt streams, XCD swizzle (R10) + EXPLICIT 3-STAGE PIPELINE with named
// slots (static indexing): OMLOAD(ks+2) || GPREP(ks+1) || CONSUME(ks).
// om loads issue 2 iters ahead, gathers 1 iter ahead -> L2 latency hides
// under interp+MFMA of the previous iteration.
// ---------------------------------------------------------------------------
struct GSlot {
    bf16x8 c00, c01, c10, c11;
    float w00, w01, w10, w11;
};

__global__ __launch_bounds__(256, 4)
void deform_mfma_kernel(const unsigned short* __restrict__ xg,  // [B][8][HW][8] bf16
                        const unsigned short* __restrict__ omg, // bf16 [B][216][HW]
                        const unsigned short* __restrict__ wpkD,// [18][4][64][8]
                        const float* __restrict__ bdcn,
                        float* __restrict__ out)
{
    const int hwid = blockIdx.x;
    const int rb   = (hwid & 7) * (BATCH * H_DIM * 2 / 8) + (hwid >> 3);

    const int x0   = (rb & 1) * 64;
    const int y    = (rb >> 1) & 127;
    const int b    = rb >> 8;
    const int tid  = threadIdx.x;
    const int lane = tid & 63;
    const int wave = tid >> 6;
    const int l15  = lane & 15;
    const int q    = lane >> 4;
    const int px0w = wave * 16;

    const unsigned short* omb = omg + (size_t)b * 216 * HW;
    const int x   = x0 + px0w + l15;
    const int pix = y * W_DIM + x;

    f32x4 acc2[4];
#pragma unroll
    for (int cf = 0; cf < 4; ++cf)
        acc2[cf] = (f32x4){0.f, 0.f, 0.f, 0.f};

    auto OMLOAD = [&](int ks, float& oy, float& ox, float& mr) {
        const int och = ((ks & 1) * 4 + q) * 9 + (ks >> 1);
        oy = bf2f(__builtin_nontemporal_load(omb + (size_t)och * HW + pix));
        ox = bf2f(__builtin_nontemporal_load(omb + (size_t)(72 + och) * HW + pix));
        mr = bf2f(__builtin_nontemporal_load(omb + (size_t)(144 + och) * HW + pix));
    };

    auto GPREP = [&](int ks, float oy, float ox, float mr, GSlot& s) {
        const int tap = ks >> 1;
        const int g   = (ks & 1) * 4 + q;
        const int dy  = tap / 3 - 1;
        const int dx  = tap % 3 - 1;
        const float mask = 1.f / (1.f + __expf(-mr));

        const float sy = oy + (float)(dy + y);
        const float sx = ox + (float)(dx + x);
        const float fy = floorf(sy);
        const float fx = floorf(sx);
        const int y0  = (int)fy;
        const int xq0 = (int)fx;
        const float ay = sy - fy;
        const float ax = sx - fx;

        const bool vy0 = (y0 >= 0) && (y0 < H_DIM);
        const bool vy1 = (y0 >= -1) && (y0 < H_DIM - 1);
        const bool vx0 = (xq0 >= 0) && (xq0 < W_DIM);
        const bool vx1 = (xq0 >= -1) && (xq0 < W_DIM - 1);

        float w00 = (1.f - ay) * (1.f - ax); if (!(vy0 && vx0)) w00 = 0.f;
        float w01 = (1.f - ay) * ax;         if (!(vy0 && vx1)) w01 = 0.f;
        float w10 = ay * (1.f - ax);         if (!(vy1 && vx0)) w10 = 0.f;
        float w11 = ay * ax;                 if (!(vy1 && vx1)) w11 = 0.f;
        s.w00 = w00 * mask; s.w01 = w01 * mask;
        s.w10 = w10 * mask; s.w11 = w11 * mask;

        const int iy0 = min(max(y0, 0), H_DIM - 1);
        const int iy1 = min(max(y0 + 1, 0), H_DIM - 1);
        const int ix0 = min(max(xq0, 0), W_DIM - 1);
        const int ix1 = min(max(xq0 + 1, 0), W_DIM - 1);

        const unsigned short* gb = xg + (size_t)(b * 8 + g) * HW * 8;
        s.c00 = *(const bf16x8*)(gb + (size_t)(iy0 * W_DIM + ix0) * 8);
        s.c01 = *(const bf16x8*)(gb + (size_t)(iy0 * W_DIM + ix1) * 8);
        s.c10 = *(const bf16x8*)(gb + (size_t)(iy1 * W_DIM + ix0) * 8);
        s.c11 = *(const bf16x8*)(gb + (size_t)(iy1 * W_DIM + ix1) * 8);
    };

    auto CONSUME = [&](int ks, GSlot& s) {
        bf16x8 av;
#pragma unroll
        for (int j = 0; j < 8; ++j) {
            float v = s.w00 * bf2f((unsigned short)s.c00[j])
                    + s.w01 * bf2f((unsigned short)s.c01[j])
                    + s.w10 * bf2f((unsigned short)s.c10[j])
                    + s.w11 * bf2f((unsigned short)s.c11[j]);
            av[j] = (short)f2bf(v);
        }
#pragma unroll
        for (int cf = 0; cf < 4; ++cf) {
            bf16x8 wfr = *(const bf16x8*)(wpkD + ((size_t)(ks * 4 + cf) * 64 + lane) * 8);
            acc2[cf] = __builtin_amdgcn_mfma_f32_16x16x32_bf16(av, wfr, acc2[cf], 0, 0, 0);
        }
    };

    float oyA, oxA, mrA, oyB, oxB, mrB;
    GSlot GA, GB;
    OMLOAD(0, oyA, oxA, mrA);
    OMLOAD(1, oyB, oxB, mrB);
    GPREP(0, oyA, oxA, mrA, GA);
#pragma unroll
    for (int ks = 0; ks < 18; ks += 2) {
        if (ks + 2 < 18) OMLOAD(ks + 2, oyA, oxA, mrA);
        GPREP(ks + 1, oyB, oxB, mrB, GB);
        CONSUME(ks, GA);
        if (ks + 3 < 18) OMLOAD(ks + 3, oyB, oxB, mrB);
        if (ks + 2 < 18) GPREP(ks + 2, oyA, oxA, mrA, GA);
        CONSUME(ks + 1, GB);
    }

#pragma unroll
    for (int cf = 0; cf < 4; ++cf) {
        const int co = cf * 16 + l15;
        const float bv = bdcn[co];
#pragma unroll
        for (int r = 0; r < 4; ++r) {
            int xs = x0 + px0w + q * 4 + r;
            __builtin_nontemporal_store(acc2[cf][r] + bv,
                out + (size_t)(b * 64 + co) * HW + y * W_DIM + xs);
        }
    }
}

// ---------------------------------------------------------------------------
// Launcher. Workspace (bytes):
//   [0, 16.8M)        in1 swizzled-NHWC bf16
//   [16.8M, 25.2M)    c1o
//   [25.2M, 33.6M)    c2o
//   [33.6M, 42.0M)    nbrg bf16 group-major [B][8][HW][8]
//   [42.0M, 70.3M)    omg bf16 [B][216][HW] (28.3M)
//   [70.3M, ...)      wpk1, wpk2, wpk3, wpkD
// ---------------------------------------------------------------------------
extern "C" void kernel_launch(void* const* d_in, const int* in_sizes, int n_in,
                              void* d_out, int out_size, void* d_ws, size_t ws_size,
                              hipStream_t stream) {
    const float* nbr  = (const float*)d_in[0];
    const float* ref  = (const float*)d_in[1];
    const float* w1   = (const float*)d_in[2];
    const float* b1   = (const float*)d_in[3];
    const float* w2   = (const float*)d_in[4];
    const float* b2   = (const float*)d_in[5];
    const float* wom  = (const float*)d_in[6];
    const float* bom  = (const float*)d_in[7];
    const float* wdcn = (const float*)d_in[8];
    const float* bdcn = (const float*)d_in[9];
    float* out = (float*)d_out;
    char* W = (char*)d_ws;

    unsigned short* in1  = (unsigned short*)(W + 0);
    unsigned short* c1o  = (unsigned short*)(W + 16777216);
    unsigned short* c2o  = (unsigned short*)(W + 25165824);
    unsigned short* nbrg = (unsigned short*)(W + 33554432);
    unsigned short* omg  = (unsigned short*)(W + 41943040);
    unsigned short* wpk1 = (unsigned short*)(W + 70254592);
    unsigned short* wpk2 = (unsigned short*)(W + 70402048);
    unsigned short* wpk3 = (unsigned short*)(W + 70475776);
    unsigned short* wpkD = (unsigned short*)(W + 70733824);

    prep_nhwc_kernel<<<dim3(HW / 64, BATCH), 256, 0, stream>>>(nbr, ref, in1, nbrg);
    pack_w_kernel<<<288, 256, 0, stream>>>(w1, wpk1, 64, 128, 4, 36);
    pack_w_kernel<<<144, 256, 0, stream>>>(w2, wpk2, 64, 64, 4, 18);
    pack_w_kernel<<<504, 256, 0, stream>>>(wom, wpk3, 216, 64, 14, 18);
    pack_w_kernel<<<144, 256, 0, stream>>>(wdcn, wpkD, 64, 64, 4, 18);

    // conv1: concat(nbr,ref) 128ch -> 64, lrelu (64-px tiles, cout-split)
    conv64_mfma_kernel<128, 36, true>
        <<<dim3(BATCH * H_DIM * 2), 256, 0, stream>>>(in1, wpk1, b1, c1o);
    // conv2: 64 -> 64, lrelu
    conv64_mfma_kernel<64, 18, true>
        <<<dim3(BATCH * H_DIM * 2), 256, 0, stream>>>(c1o, wpk2, b2, c2o);

    // conv3 -> om bf16 global (coalesced, cout-split waves)
    conv3om_kernel<<<dim3(BATCH * H_DIM * 2), 256, 0, stream>>>(
        c2o, wpk3, bom, omg);
    // deformable conv (3-stage pipeline + group-major + nt + XCD swizzle)
    deform_mfma_kernel<<<dim3(BATCH * H_DIM * 2), 256, 0, stream>>>(
        nbrg, omg, wpkD, bdcn, out);
}

// Round 13
// 100.002 us; speedup vs baseline: 1.7331x; 1.2183x over previous
//
#include <hip/hip_runtime.h>
#include <hip/hip_bf16.h>
#include <math.h>

#define H_DIM 128
#define W_DIM 128
#define BATCH 4
#define HW (H_DIM * W_DIM)

typedef __attribute__((ext_vector_type(8))) short bf16x8;
typedef __attribute__((ext_vector_type(4))) float f32x4;
typedef __attribute__((ext_vector_type(4))) unsigned int u32x4;

static __device__ __forceinline__ unsigned short f2bf(float f) {
    __hip_bfloat16 h = __float2bfloat16(f);   // RNE
    return *reinterpret_cast<unsigned short*>(&h);
}
static __device__ __forceinline__ float bf2f(unsigned short u) {
    return __uint_as_float(((unsigned int)u) << 16);
}

// ---------------------------------------------------------------------------
// Build swizzled-NHWC bf16 concat input [B][H][W][128]  AND  group-major
// nbr copy [B][8g][HW][8ch] in one pass (nbr already staged in LDS).
// Swizzle: unit ut of column x stored at (ut&8) | ((ut&7) ^ ((x+1)&7)).
// ---------------------------------------------------------------------------
__global__ __launch_bounds__(256)
void prep_nhwc_kernel(const float* __restrict__ nbr, const float* __restrict__ ref,
                      unsigned short* __restrict__ dst,
                      unsigned short* __restrict__ gmaj) {
    __shared__ float s[128][65];   // 33.3 KB
    const int b  = blockIdx.y;
    const int p0 = blockIdx.x * 64;          // aligned 64 px, same row y
    const int t  = threadIdx.x;
    const int px = t & 63;
#pragma unroll
    for (int it = 0; it < 32; ++it) {
        int c = it * 4 + (t >> 6);           // 0..127
        const float* src = (c < 64) ? nbr : ref;
        int cs = c & 63;
        s[c][px] = src[(size_t)(b * 64 + cs) * HW + p0 + px];
    }
    __syncthreads();
#pragma unroll
    for (int it = 0; it < 4; ++it) {
        int idx = it * 256 + t;              // p*16 + ut
        int p  = idx >> 4;
        int ut = idx & 15;
        int x  = (p0 + p) & 127;
        int key = (x + 1) & 7;
        int cpos = (ut & 8) | ((ut & 7) ^ key);
        bf16x8 v;
#pragma unroll
        for (int j = 0; j < 8; ++j)
            v[j] = (short)f2bf(s[ut * 8 + j][p]);
        *(bf16x8*)(dst + ((size_t)(b * HW + p0 + p) * 128 + cpos * 8)) = v;
    }
    // group-major nbr output (channels 0..63 of s)
#pragma unroll
    for (int it = 0; it < 2; ++it) {
        int idx = it * 256 + t;       // g*64 + px (px fastest -> coalesced)
        int g   = idx >> 6;
        int p2  = idx & 63;
        bf16x8 v;
#pragma unroll
        for (int j = 0; j < 8; ++j)
            v[j] = (short)f2bf(s[g * 8 + j][p2]);
        *(bf16x8*)(gmaj + ((size_t)(b * 8 + g) * HW + p0 + p2) * 8) = v;
    }
}

// ---------------------------------------------------------------------------
// ALL weight packs in one launch (was 4 tiny serialized launches).
// Same per-element transform as before: [COUT][CIN][3][3] fp32 -> MFMA
// B-fragment order bf16, k = ks*32 + (lane>>4)*8 + j, t = k/CIN, ci = k%CIN.
// ---------------------------------------------------------------------------
__global__ void pack_all_kernel(const float* __restrict__ w1, const float* __restrict__ w2,
                                const float* __restrict__ wom, const float* __restrict__ wdcn,
                                unsigned short* __restrict__ wpk1, unsigned short* __restrict__ wpk2,
                                unsigned short* __restrict__ wpk3, unsigned short* __restrict__ wpkD) {
    int idx = blockIdx.x * 256 + threadIdx.x;
    const int N1 = 73728, N2 = 36864, N3 = 129024, N4 = 36864;
    const float* w; unsigned short* dst; int CIN, NCF, COUT;
    if (idx < N1)                { w = w1;   dst = wpk1; CIN = 128; NCF = 4;  COUT = 64; }
    else if (idx < N1+N2)        { idx -= N1;       w = w2;   dst = wpk2; CIN = 64; NCF = 4;  COUT = 64; }
    else if (idx < N1+N2+N3)     { idx -= N1+N2;    w = wom;  dst = wpk3; CIN = 64; NCF = 14; COUT = 216; }
    else if (idx < N1+N2+N3+N4)  { idx -= N1+N2+N3; w = wdcn; dst = wpkD; CIN = 64; NCF = 4;  COUT = 64; }
    else return;
    int j    = idx & 7;
    int lane = (idx >> 3) & 63;
    int frag = idx >> 9;
    int cf   = frag % NCF;
    int ks   = frag / NCF;
    int co = cf * 16 + (lane & 15);
    int k  = ks * 32 + (lane >> 4) * 8 + j;
    int t  = k / CIN;
    int ci = k % CIN;
    float v = (co < COUT) ? w[((size_t)co * CIN + ci) * 9 + t] : 0.f;
    dst[idx] = f2bf(v);
}

// ---------------------------------------------------------------------------
// Implicit-GEMM 3x3 conv, 64-px tiles, COUT-SPLIT waves (conv1 / conv2).
// ---------------------------------------------------------------------------
template<int CIN, int NKS, bool RELU>
__global__ __launch_bounds__(256, 3)
void conv64_mfma_kernel(const unsigned short* __restrict__ in,   // swizzled NHWC bf16
                        const unsigned short* __restrict__ wpk,  // [NKS][4][64][8]
                        const float* __restrict__ bias,
                        unsigned short* __restrict__ out)
{
    constexpr int ROWB = 66 * CIN * 2;
    __shared__ __align__(16) char smem[3 * ROWB];

    const int rb   = blockIdx.x;        // ((b*H + y)<<1) | half
    const int x0   = (rb & 1) * 64;
    const int y    = (rb >> 1) & 127;
    const int b    = rb >> 8;
    const int tid  = threadIdx.x;
    const int lane = tid & 63;
    const int wave = tid >> 6;          // cout-frag index
    const int l15  = lane & 15;
    const int q    = lane >> 4;
    const u32x4 zv = {0u, 0u, 0u, 0u};

    const int lstart = (x0 == 0) ? 1 : 0;
    const int lzero  = (x0 == 0) ? 0 : 65;
    for (int dy = 0; dy < 3; ++dy) {
        int yy = y + dy - 1;
        char* dstrow = smem + dy * ROWB;
        if (yy >= 0 && yy < H_DIM) {
            const char* src = (const char*)(in +
                ((size_t)(b * H_DIM + yy) * W_DIM + (x0 - 1 + lstart)) * CIN);
            for (int i = tid * 16; i < 65 * CIN * 2; i += 256 * 16)
                *(u32x4*)(dstrow + lstart * CIN * 2 + i) = *(const u32x4*)(src + i);
            if (tid < CIN / 8)
                *(u32x4*)(dstrow + lzero * CIN * 2 + tid * 16) = zv;
        } else {
            for (int i = tid * 16; i < 66 * CIN * 2; i += 256 * 16)
                *(u32x4*)(dstrow + i) = zv;
        }
    }
    __syncthreads();

    f32x4 acc[4];
#pragma unroll
    for (int pf = 0; pf < 4; ++pf)
        acc[pf] = (f32x4){0.f, 0.f, 0.f, 0.f};

#pragma unroll
    for (int ks = 0; ks < NKS; ++ks) {
        const int t   = ks / (CIN / 32);
        const int ci0 = (ks % (CIN / 32)) * 32;
        const int dy = t / 3, dx = t % 3;
        const int u  = (ci0 >> 3) + q;
        bf16x8 a[4];
#pragma unroll
        for (int pf = 0; pf < 4; ++pf) {
            const int l = pf * 16 + l15 + dx;
            const int upos = u ^ (l & 7);
            a[pf] = *(const bf16x8*)(smem + dy * ROWB + (l * CIN + upos * 8) * 2);
        }
        bf16x8 wfr = *(const bf16x8*)(wpk + ((size_t)(ks * 4 + wave) * 64 + lane) * 8);
#pragma unroll
        for (int pf = 0; pf < 4; ++pf)
            acc[pf] = __builtin_amdgcn_mfma_f32_16x16x32_bf16(a[pf], wfr, acc[pf], 0, 0, 0);
    }

    const int co = wave * 16 + l15;
    const float bv = bias[co];
#pragma unroll
    for (int pf = 0; pf < 4; ++pf)
#pragma unroll
        for (int r = 0; r < 4; ++r) {
            int x = x0 + pf * 16 + q * 4 + r;
            float v = acc[pf][r] + bv;
            if (RELU) v = (v >= 0.f) ? v : 0.1f * v;
            int cpos = (((co >> 3) ^ ((x + 1) & 7)) << 3) | (co & 7);
            out[((size_t)(b * H_DIM + y) * W_DIM + x) * 64 + cpos] = f2bf(v);
        }
}

// ---------------------------------------------------------------------------
// FUSED conv3 (216 couts) + modulated deformable conv. R5 retried with all
// fixes: 64-px blocks; (256,3) so phase-2's gather pipeline has ~170 VGPR
// (R5 died at 64); phase-1 acc (AGPR) dies before phase-2 peaks; 3-stage
// OMLOAD||GPREP||CONSUME pipeline (OMLOAD now an LDS read); group-major
// gathers; XCD swizzle. om never touches HBM (-56.6 MB round trip).
// LDS union: staging 25344 B | om [216][72] bf16 = 31104 B.
// ---------------------------------------------------------------------------
struct GSlot {
    bf16x8 c00, c01, c10, c11;
    float w00, w01, w10, w11;
};

__global__ __launch_bounds__(256, 3)
void fused_om_deform_kernel(const unsigned short* __restrict__ in,   // c2o swizzled NHWC
                            const unsigned short* __restrict__ xg,   // nbr [B][8][HW][8]
                            const unsigned short* __restrict__ wpk3, // [18][14][64][8]
                            const unsigned short* __restrict__ wpkD, // [18][4][64][8]
                            const float* __restrict__ bom,
                            const float* __restrict__ bdcn,
                            float* __restrict__ out)
{
    constexpr int ROWB = 66 * 128;
    __shared__ __align__(16) char smem[216 * 72 * 2];   // 31104 B union
    unsigned short* om_lds = (unsigned short*)smem;

    const int hwid = blockIdx.x;
    const int rb   = (hwid & 7) * (BATCH * H_DIM * 2 / 8) + (hwid >> 3);
    const int x0   = (rb & 1) * 64;
    const int y    = (rb >> 1) & 127;
    const int b    = rb >> 8;
    const int tid  = threadIdx.x;
    const int lane = tid & 63;
    const int wave = tid >> 6;
    const int l15  = lane & 15;
    const int q    = lane >> 4;
    const u32x4 zv = {0u, 0u, 0u, 0u};

    // ---- phase 1a: stage c2o rows (swizzled, linear copy) ----
    const int lstart = (x0 == 0) ? 1 : 0;
    const int lzero  = (x0 == 0) ? 0 : 65;
    for (int dy = 0; dy < 3; ++dy) {
        int yy = y + dy - 1;
        char* dstrow = smem + dy * ROWB;
        if (yy >= 0 && yy < H_DIM) {
            const char* src = (const char*)(in +
                ((size_t)(b * H_DIM + yy) * W_DIM + (x0 - 1 + lstart)) * 64);
            for (int i = tid * 16; i < 65 * 128; i += 256 * 16)
                *(u32x4*)(dstrow + lstart * 128 + i) = *(const u32x4*)(src + i);
            if (tid < 8)
                *(u32x4*)(dstrow + lzero * 128 + tid * 16) = zv;
        } else {
            for (int i = tid * 16; i < 66 * 128; i += 256 * 16)
                *(u32x4*)(dstrow + i) = zv;
        }
    }
    __syncthreads();

    // ---- phase 1b: conv3 cout-split (wave w -> cf {w, w+4, w+8, w+12}) ----
    {
        f32x4 acc[4][4];   // [pf][cfi]
#pragma unroll
        for (int pf = 0; pf < 4; ++pf)
#pragma unroll
            for (int cfi = 0; cfi < 4; ++cfi)
                acc[pf][cfi] = (f32x4){0.f, 0.f, 0.f, 0.f};

#pragma unroll
        for (int ks = 0; ks < 18; ++ks) {
            const int t   = ks >> 1;
            const int ci0 = (ks & 1) * 32;
            const int dy = t / 3, dx = t % 3;
            bf16x8 a[4];
#pragma unroll
            for (int pf = 0; pf < 4; ++pf) {
                const int l = pf * 16 + l15 + dx;
                const int upos = ((ci0 >> 3) + q) ^ (l & 7);
                a[pf] = *(const bf16x8*)(smem + dy * ROWB + (l * 64 + upos * 8) * 2);
            }
#pragma unroll
            for (int cfi = 0; cfi < 4; ++cfi) {
                const int cf = wave + cfi * 4;
                if (cfi < 3 || wave < 2) {            // cf < 14 (wave-uniform)
                    bf16x8 wfr = *(const bf16x8*)(wpk3 + ((size_t)(ks * 14 + cf) * 64 + lane) * 8);
#pragma unroll
                    for (int pf = 0; pf < 4; ++pf)
                        acc[pf][cfi] = __builtin_amdgcn_mfma_f32_16x16x32_bf16(
                            a[pf], wfr, acc[pf][cfi], 0, 0, 0);
                }
            }
        }
        __syncthreads();   // staging dead; om region aliases it

        // ---- om slices -> LDS bf16 [216][72] ----
#pragma unroll
        for (int cfi = 0; cfi < 4; ++cfi) {
            const int cf = wave + cfi * 4;
            if (cfi < 3 || wave < 2) {
                const int co = cf * 16 + l15;
                if (co < 216) {
                    const float bv = bom[co];
#pragma unroll
                    for (int pf = 0; pf < 4; ++pf)
#pragma unroll
                        for (int r = 0; r < 4; ++r) {
                            int xl = pf * 16 + q * 4 + r;
                            om_lds[co * 72 + xl] = f2bf(acc[pf][cfi][r] + bv);
                        }
                }
            }
        }
    }
    __syncthreads();

    // ---- phase 2: deform, 3-stage pipeline, om from LDS ----
    const int px0w = wave * 16;
    const int x    = x0 + px0w + l15;
    const int xl   = px0w + l15;

    f32x4 acc2[4];
#pragma unroll
    for (int cf = 0; cf < 4; ++cf)
        acc2[cf] = (f32x4){0.f, 0.f, 0.f, 0.f};

    auto OMLOAD = [&](int ks, float& oy, float& ox, float& mr) {
        const int och = ((ks & 1) * 4 + q) * 9 + (ks >> 1);
        oy = bf2f(om_lds[och * 72 + xl]);
        ox = bf2f(om_lds[(72 + och) * 72 + xl]);
        mr = bf2f(om_lds[(144 + och) * 72 + xl]);
    };

    auto GPREP = [&](int ks, float oy, float ox, float mr, GSlot& s) {
        const int tap = ks >> 1;
        const int g   = (ks & 1) * 4 + q;
        const int dy  = tap / 3 - 1;
        const int dx  = tap % 3 - 1;
        const float mask = 1.f / (1.f + __expf(-mr));

        const float sy = oy + (float)(dy + y);
        const float sx = ox + (float)(dx + x);
        const float fy = floorf(sy);
        const float fx = floorf(sx);
        const int y0  = (int)fy;
        const int xq0 = (int)fx;
        const float ay = sy - fy;
        const float ax = sx - fx;

        const bool vy0 = (y0 >= 0) && (y0 < H_DIM);
        const bool vy1 = (y0 >= -1) && (y0 < H_DIM - 1);
        const bool vx0 = (xq0 >= 0) && (xq0 < W_DIM);
        const bool vx1 = (xq0 >= -1) && (xq0 < W_DIM - 1);

        float w00 = (1.f - ay) * (1.f - ax); if (!(vy0 && vx0)) w00 = 0.f;
        float w01 = (1.f - ay) * ax;         if (!(vy0 && vx1)) w01 = 0.f;
        float w10 = ay * (1.f - ax);         if (!(vy1 && vx0)) w10 = 0.f;
        float w11 = ay * ax;                 if (!(vy1 && vx1)) w11 = 0.f;
        s.w00 = w00 * mask; s.w01 = w01 * mask;
        s.w10 = w10 * mask; s.w11 = w11 * mask;

        const int iy0 = min(max(y0, 0), H_DIM - 1);
        const int iy1 = min(max(y0 + 1, 0), H_DIM - 1);
        const int ix0 = min(max(xq0, 0), W_DIM - 1);
        const int ix1 = min(max(xq0 + 1, 0), W_DIM - 1);

        const unsigned short* gb = xg + (size_t)(b * 8 + g) * HW * 8;
        s.c00 = *(const bf16x8*)(gb + (size_t)(iy0 * W_DIM + ix0) * 8);
        s.c01 = *(const bf16x8*)(gb + (size_t)(iy0 * W_DIM + ix1) * 8);
        s.c10 = *(const bf16x8*)(gb + (size_t)(iy1 * W_DIM + ix0) * 8);
        s.c11 = *(const bf16x8*)(gb + (size_t)(iy1 * W_DIM + ix1) * 8);
    };

    auto CONSUME = [&](int ks, GSlot& s) {
        bf16x8 av;
#pragma unroll
        for (int j = 0; j < 8; ++j) {
            float v = s.w00 * bf2f((unsigned short)s.c00[j])
                    + s.w01 * bf2f((unsigned short)s.c01[j])
                    + s.w10 * bf2f((unsigned short)s.c10[j])
                    + s.w11 * bf2f((unsigned short)s.c11[j]);
            av[j] = (short)f2bf(v);
        }
#pragma unroll
        for (int cf = 0; cf < 4; ++cf) {
            bf16x8 wfr = *(const bf16x8*)(wpkD + ((size_t)(ks * 4 + cf) * 64 + lane) * 8);
            acc2[cf] = __builtin_amdgcn_mfma_f32_16x16x32_bf16(av, wfr, acc2[cf], 0, 0, 0);
        }
    };

    float oyA, oxA, mrA, oyB, oxB, mrB;
    GSlot GA, GB;
    OMLOAD(0, oyA, oxA, mrA);
    OMLOAD(1, oyB, oxB, mrB);
    GPREP(0, oyA, oxA, mrA, GA);
#pragma unroll
    for (int ks = 0; ks < 18; ks += 2) {
        if (ks + 2 < 18) OMLOAD(ks + 2, oyA, oxA, mrA);
        GPREP(ks + 1, oyB, oxB, mrB, GB);
        CONSUME(ks, GA);
        if (ks + 3 < 18) OMLOAD(ks + 3, oyB, oxB, mrB);
        if (ks + 2 < 18) GPREP(ks + 2, oyA, oxA, mrA, GA);
        CONSUME(ks + 1, GB);
    }

#pragma unroll
    for (int cf = 0; cf < 4; ++cf) {
        const int co = cf * 16 + l15;
        const float bv = bdcn[co];
#pragma unroll
        for (int r = 0; r < 4; ++r) {
            int xs = x0 + px0w + q * 4 + r;
            __builtin_nontemporal_store(acc2[cf][r] + bv,
                out + (size_t)(b * 64 + co) * HW + y * W_DIM + xs);
        }
    }
}

// ---------------------------------------------------------------------------
// Launcher. 5 dispatches (was 9). Workspace (bytes):
//   [0, 16.8M)        in1 swizzled-NHWC bf16
//   [16.8M, 25.2M)    c1o
//   [25.2M, 33.6M)    c2o
//   [33.6M, 42.0M)    nbrg bf16 group-major [B][8][HW][8]
//   [42.0M, ...)      wpk1, wpk2, wpk3, wpkD   (om lives in LDS now)
// ---------------------------------------------------------------------------
extern "C" void kernel_launch(void* const* d_in, const int* in_sizes, int n_in,
                              void* d_out, int out_size, void* d_ws, size_t ws_size,
                              hipStream_t stream) {
    const float* nbr  = (const float*)d_in[0];
    const float* ref  = (const float*)d_in[1];
    const float* w1   = (const float*)d_in[2];
    const float* b1   = (const float*)d_in[3];
    const float* w2   = (const float*)d_in[4];
    const float* b2   = (const float*)d_in[5];
    const float* wom  = (const float*)d_in[6];
    const float* bom  = (const float*)d_in[7];
    const float* wdcn = (const float*)d_in[8];
    const float* bdcn = (const float*)d_in[9];
    float* out = (float*)d_out;
    char* W = (char*)d_ws;

    unsigned short* in1  = (unsigned short*)(W + 0);
    unsigned short* c1o  = (unsigned short*)(W + 16777216);
    unsigned short* c2o  = (unsigned short*)(W + 25165824);
    unsigned short* nbrg = (unsigned short*)(W + 33554432);
    unsigned short* wpk1 = (unsigned short*)(W + 41943040);
    unsigned short* wpk2 = (unsigned short*)(W + 42090496);
    unsigned short* wpk3 = (unsigned short*)(W + 42164224);
    unsigned short* wpkD = (unsigned short*)(W + 42422272);

    prep_nhwc_kernel<<<dim3(HW / 64, BATCH), 256, 0, stream>>>(nbr, ref, in1, nbrg);
    pack_all_kernel<<<1080, 256, 0, stream>>>(w1, w2, wom, wdcn,
                                              wpk1, wpk2, wpk3, wpkD);

    // conv1: concat(nbr,ref) 128ch -> 64, lrelu (64-px tiles, cout-split)
    conv64_mfma_kernel<128, 36, true>
        <<<dim3(BATCH * H_DIM * 2), 256, 0, stream>>>(in1, wpk1, b1, c1o);
    // conv2: 64 -> 64, lrelu
    conv64_mfma_kernel<64, 18, true>
        <<<dim3(BATCH * H_DIM * 2), 256, 0, stream>>>(c1o, wpk2, b2, c2o);

    // fused conv3 + deformable conv (om in LDS; pipeline; group-major; XCD)
    fused_om_deform_kernel<<<dim3(BATCH * H_DIM * 2), 256, 0, stream>>>(
        c2o, nbrg, wpk3, wpkD, bom, bdcn, out);
}